// Round 1
// baseline (441.462 us; speedup 1.0000x reference)
//
#include <hip/hip_runtime.h>

// GCN: h1 = relu(Agg(x@W1) + b1); h2 = Agg(h1@W2) + b2; out = h2@Wc + bc
// Agg = symmetric-normalized adjacency with self-loops (PyG GCNConv).
// Strategy: build dst-CSR (hist -> scan -> fill), then gather-based segment
// sum (no float atomics). All fp32 (no fp32 MFMA on CDNA4; dense is tiny).

#define DIN 128
#define HID 128
#define FOUT 64

__global__ __launch_bounds__(256) void hist_kernel(
    const int* __restrict__ ei, int E, int* __restrict__ counts) {
  int e = blockIdx.x * 256 + threadIdx.x;
  if (e < E) atomicAdd(&counts[ei[E + e]], 1);
}

// Single-block exclusive scan over counts[N] -> offsets[N+1]
__global__ __launch_bounds__(1024) void scan_kernel(
    const int* __restrict__ counts, int N, int E, int* __restrict__ offsets) {
  __shared__ int sums[1024];
  int t = threadIdx.x;
  int chunk = (N + 1023) >> 10;
  int i0 = t * chunk;
  int i1 = min(i0 + chunk, N);
  int s = 0;
  for (int i = i0; i < i1; ++i) s += counts[i];
  sums[t] = s;
  __syncthreads();
  for (int off = 1; off < 1024; off <<= 1) {
    int v = 0;
    if (t >= off) v = sums[t - off];
    __syncthreads();
    sums[t] += v;
    __syncthreads();
  }
  int run = sums[t] - s;  // exclusive prefix of this thread's chunk
  for (int i = i0; i < i1; ++i) {
    offsets[i] = run;
    run += counts[i];
  }
  if (t == 0) offsets[N] = E;
}

__global__ __launch_bounds__(256) void node_init_kernel(
    const int* __restrict__ counts, const int* __restrict__ offsets,
    float* __restrict__ dis, int* __restrict__ cursor, int N) {
  int i = blockIdx.x * 256 + threadIdx.x;
  if (i < N) {
    dis[i] = rsqrtf((float)counts[i] + 1.0f);  // deg includes self-loop
    cursor[i] = offsets[i];
  }
}

__global__ __launch_bounds__(256) void fill_kernel(
    const int* __restrict__ ei, int E, int* __restrict__ cursor,
    int* __restrict__ csr) {
  int e = blockIdx.x * 256 + threadIdx.x;
  if (e < E) {
    int s = ei[e];
    int d = ei[E + e];
    int p = atomicAdd(&cursor[d], 1);
    csr[p] = s;
  }
}

__device__ inline void fma4(float4& c, float a, const float4& w) {
  c.x = fmaf(a, w.x, c.x);
  c.y = fmaf(a, w.y, c.y);
  c.z = fmaf(a, w.z, c.z);
  c.w = fmaf(a, w.w, c.w);
}

// C[M x NCOL] = A[M x K] @ W[K x NCOL] (+bias). W staged in LDS, A tile in LDS.
template <int K, int NCOL, bool BIAS>
__global__ __launch_bounds__(256) void gemm_kernel(
    const float* __restrict__ A, const float* __restrict__ W,
    const float* __restrict__ bias, float* __restrict__ C, int M) {
  constexpr int ROWS = 32;
  constexpr int KP = (NCOL == 128) ? K : (K + 4);  // pad only when needed (LDS budget)
  __shared__ __align__(16) float Ws[K * NCOL];
  __shared__ __align__(16) float As[ROWS * KP];
  int tid = threadIdx.x;
  int row0 = blockIdx.x * ROWS;

  const float4* W4 = (const float4*)W;
  float4* Ws4 = (float4*)Ws;
  constexpr int WV = K * NCOL / 4;
  for (int i = tid; i < WV; i += 256) Ws4[i] = W4[i];

  constexpr int AV = ROWS * (K / 4);
  for (int i = tid; i < AV; i += 256) {
    int r = i / (K / 4);
    int kk = i % (K / 4);
    float4 v = make_float4(0.f, 0.f, 0.f, 0.f);
    if (row0 + r < M) v = *(const float4*)&A[(size_t)(row0 + r) * K + kk * 4];
    *(float4*)&As[r * KP + kk * 4] = v;
  }
  __syncthreads();

  constexpr int CG = NCOL / 4;   // col groups of 4
  constexpr int RS = 256 / CG;   // row slots
  constexpr int NR = ROWS / RS;  // rows per thread
  int cg = tid % CG;
  int rslot = tid / CG;

  float4 acc[NR];
#pragma unroll
  for (int rr = 0; rr < NR; ++rr) acc[rr] = make_float4(0.f, 0.f, 0.f, 0.f);

  for (int k = 0; k < K; k += 4) {
    float4 w0 = *(const float4*)&Ws[(k + 0) * NCOL + cg * 4];
    float4 w1 = *(const float4*)&Ws[(k + 1) * NCOL + cg * 4];
    float4 w2 = *(const float4*)&Ws[(k + 2) * NCOL + cg * 4];
    float4 w3 = *(const float4*)&Ws[(k + 3) * NCOL + cg * 4];
#pragma unroll
    for (int rr = 0; rr < NR; ++rr) {
      int r = rslot * NR + rr;
      float4 a = *(const float4*)&As[r * KP + k];
      fma4(acc[rr], a.x, w0);
      fma4(acc[rr], a.y, w1);
      fma4(acc[rr], a.z, w2);
      fma4(acc[rr], a.w, w3);
    }
  }

#pragma unroll
  for (int rr = 0; rr < NR; ++rr) {
    int row = row0 + rslot * NR + rr;
    if (row < M) {
      float4 v = acc[rr];
      if (BIAS) {
        v.x += bias[cg * 4 + 0];
        v.y += bias[cg * 4 + 1];
        v.z += bias[cg * 4 + 2];
        v.w += bias[cg * 4 + 3];
      }
      *(float4*)&C[(size_t)row * NCOL + cg * 4] = v;
    }
  }
}

// Gather-based segment sum: out[n][f] = sum_{s in N(n)} hw[s][f]*dis[s]*dis[n]
//                                     + hw[n][f]*dis[n]^2  (+bias, opt relu)
template <int F, bool RELU>
__global__ __launch_bounds__(256) void gather_kernel(
    const float* __restrict__ hw, const float* __restrict__ dis,
    const int* __restrict__ off, const int* __restrict__ csr,
    const float* __restrict__ bias, float* __restrict__ out, int N) {
  constexpr int NPB = 256 / F;
  int local = threadIdx.x / F;
  int f = threadIdx.x % F;
  int n = blockIdx.x * NPB + local;
  if (n >= N) return;
  float dn = dis[n];
  float acc = hw[(size_t)n * F + f] * dn * dn;  // self loop
  int j0 = off[n];
  int j1 = off[n + 1];
  int j = j0;
  for (; j + 4 <= j1; j += 4) {
    int s0 = csr[j + 0];
    int s1 = csr[j + 1];
    int s2 = csr[j + 2];
    int s3 = csr[j + 3];
    float w0 = dis[s0] * dn;
    float w1 = dis[s1] * dn;
    float w2 = dis[s2] * dn;
    float w3 = dis[s3] * dn;
    float v0 = hw[(size_t)s0 * F + f];
    float v1 = hw[(size_t)s1 * F + f];
    float v2 = hw[(size_t)s2 * F + f];
    float v3 = hw[(size_t)s3 * F + f];
    acc = fmaf(v0, w0, acc);
    acc = fmaf(v1, w1, acc);
    acc = fmaf(v2, w2, acc);
    acc = fmaf(v3, w3, acc);
  }
  for (; j < j1; ++j) {
    int s = csr[j];
    acc = fmaf(hw[(size_t)s * F + f], dis[s] * dn, acc);
  }
  acc += bias[f];
  if (RELU) acc = fmaxf(acc, 0.f);
  out[(size_t)n * F + f] = acc;
}

extern "C" void kernel_launch(void* const* d_in, const int* in_sizes, int n_in,
                              void* d_out, int out_size, void* d_ws,
                              size_t ws_size, hipStream_t stream) {
  const float* x = (const float*)d_in[0];
  const int* ei = (const int*)d_in[1];
  const float* W1 = (const float*)d_in[2];
  const float* b1 = (const float*)d_in[3];
  const float* W2 = (const float*)d_in[4];
  const float* b2 = (const float*)d_in[5];
  const float* Wc = (const float*)d_in[6];
  const float* bc = (const float*)d_in[7];

  int N = in_sizes[0] / DIN;
  int E = in_sizes[1] / 2;

  // workspace layout (256B-aligned regions); hw2 aliases hw1 (dead by then)
  char* w = (char*)d_ws;
  size_t off = 0;
  auto alloc = [&](size_t bytes) {
    char* p = w + off;
    off += (bytes + 255) & ~(size_t)255;
    return p;
  };
  int* counts = (int*)alloc((size_t)N * 4);
  int* offsets = (int*)alloc((size_t)(N + 1) * 4);
  int* cursor = (int*)alloc((size_t)N * 4);
  int* csr = (int*)alloc((size_t)E * 4);
  float* dis = (float*)alloc((size_t)N * 4);
  float* hw1 = (float*)alloc((size_t)N * DIN * 4);
  float* h1 = (float*)alloc((size_t)N * HID * 4);
  float* hw2 = hw1;  // alias: hw1 dead after gather1

  float* out_h2 = (float*)d_out;              // output 0: h2 [N x 64]
  float* out_y = out_h2 + (size_t)N * FOUT;   // output 1: out [N x 64]

  hipMemsetAsync(counts, 0, (size_t)N * 4, stream);

  int egrid = (E + 255) / 256;
  int ngrid = (N + 255) / 256;
  int ggrid = (N + 31) / 32;

  hist_kernel<<<egrid, 256, 0, stream>>>(ei, E, counts);
  scan_kernel<<<1, 1024, 0, stream>>>(counts, N, E, offsets);
  node_init_kernel<<<ngrid, 256, 0, stream>>>(counts, offsets, dis, cursor, N);
  fill_kernel<<<egrid, 256, 0, stream>>>(ei, E, cursor, csr);

  // layer 1: hw1 = x @ W1 ; h1 = relu(Agg(hw1) + b1)
  gemm_kernel<DIN, HID, false><<<ggrid, 256, 0, stream>>>(x, W1, nullptr, hw1, N);
  gather_kernel<HID, true><<<(N + 1) / 2, 256, 0, stream>>>(hw1, dis, offsets, csr, b1, h1, N);

  // layer 2: hw2 = h1 @ W2 ; h2 = Agg(hw2) + b2  -> d_out[0 : N*64]
  gemm_kernel<HID, FOUT, false><<<ggrid, 256, 0, stream>>>(h1, W2, nullptr, hw2, N);
  gather_kernel<FOUT, false><<<(N + 3) / 4, 256, 0, stream>>>(hw2, dis, offsets, csr, b2, out_h2, N);

  // head: out = h2 @ Wc + bc -> d_out[N*64 : 2*N*64]
  gemm_kernel<FOUT, FOUT, true><<<ggrid, 256, 0, stream>>>(out_h2, Wc, bc, out_y, N);
}

// Round 2
// 374.453 us; speedup vs baseline: 1.1790x; 1.1790x over previous
//
#include <hip/hip_runtime.h>

// GCN: h1 = relu(Agg(x@W1) + b1); h2 = Agg(h1@W2) + b2; out = h2@Wc + bc
// Agg = symmetric-normalized adjacency with self-loops (PyG GCNConv).
// CSR build: hist -> 3-level parallel scan (fused node_init) -> fill.
// Aggregation: gather-based segment sum (no float atomics).

#define DIN 128
#define HID 128
#define FOUT 64

__global__ __launch_bounds__(256) void hist_kernel(
    const int* __restrict__ ei, int E, int* __restrict__ counts) {
  int e = blockIdx.x * 256 + threadIdx.x;
  if (e < E) atomicAdd(&counts[ei[E + e]], 1);
}

// Level 1: per-block sums of 256-count chunks.
__global__ __launch_bounds__(256) void block_sum_kernel(
    const int* __restrict__ counts, int N, int* __restrict__ blockSums) {
  int i = blockIdx.x * 256 + threadIdx.x;
  int v = (i < N) ? counts[i] : 0;
#pragma unroll
  for (int off = 32; off > 0; off >>= 1) v += __shfl_down(v, off, 64);
  __shared__ int ws[4];
  if ((threadIdx.x & 63) == 0) ws[threadIdx.x >> 6] = v;
  __syncthreads();
  if (threadIdx.x == 0)
    blockSums[blockIdx.x] = ws[0] + ws[1] + ws[2] + ws[3];
}

// Level 2: single-block exclusive scan of up to 1024 block sums.
__global__ __launch_bounds__(1024) void scan_blocksums_kernel(
    int* __restrict__ blockSums, int G) {
  __shared__ int s[1024];
  int t = threadIdx.x;
  int v = (t < G) ? blockSums[t] : 0;
  s[t] = v;
  __syncthreads();
  for (int off = 1; off < 1024; off <<= 1) {
    int u = 0;
    if (t >= off) u = s[t - off];
    __syncthreads();
    s[t] += u;
    __syncthreads();
  }
  if (t < G) blockSums[t] = s[t] - v;  // exclusive
}

// Level 3: re-scan chunk, add block offset; fused node_init (dis, cursor).
__global__ __launch_bounds__(256) void scan_apply_kernel(
    const int* __restrict__ counts, const int* __restrict__ blockSums, int N,
    int E, int* __restrict__ offsets, int* __restrict__ cursor,
    float* __restrict__ dis) {
  int t = threadIdx.x;
  int i = blockIdx.x * 256 + t;
  int c = (i < N) ? counts[i] : 0;
  __shared__ int s[256];
  s[t] = c;
  __syncthreads();
  for (int off = 1; off < 256; off <<= 1) {
    int u = 0;
    if (t >= off) u = s[t - off];
    __syncthreads();
    s[t] += u;
    __syncthreads();
  }
  int excl = s[t] - c + blockSums[blockIdx.x];
  if (i < N) {
    offsets[i] = excl;
    cursor[i] = excl;
    dis[i] = rsqrtf((float)c + 1.0f);  // deg includes self-loop
  }
  if (i == N - 1) offsets[N] = E;
}

__global__ __launch_bounds__(256) void fill_kernel(
    const int* __restrict__ ei, int E, int* __restrict__ cursor,
    int* __restrict__ csr) {
  int e = blockIdx.x * 256 + threadIdx.x;
  if (e < E) {
    int s = ei[e];
    int d = ei[E + e];
    int p = atomicAdd(&cursor[d], 1);
    csr[p] = s;
  }
}

__device__ inline void fma4(float4& c, float a, const float4& w) {
  c.x = fmaf(a, w.x, c.x);
  c.y = fmaf(a, w.y, c.y);
  c.z = fmaf(a, w.z, c.z);
  c.w = fmaf(a, w.w, c.w);
}

// C[M x NCOL] = A[M x K] @ W[K x NCOL] (+bias). W staged in LDS, A tile in LDS.
template <int K, int NCOL, bool BIAS>
__global__ __launch_bounds__(256) void gemm_kernel(
    const float* __restrict__ A, const float* __restrict__ W,
    const float* __restrict__ bias, float* __restrict__ C, int M) {
  constexpr int ROWS = 32;
  constexpr int KP = (NCOL == 128) ? K : (K + 4);
  __shared__ __align__(16) float Ws[K * NCOL];
  __shared__ __align__(16) float As[ROWS * KP];
  int tid = threadIdx.x;
  int row0 = blockIdx.x * ROWS;

  const float4* W4 = (const float4*)W;
  float4* Ws4 = (float4*)Ws;
  constexpr int WV = K * NCOL / 4;
  for (int i = tid; i < WV; i += 256) Ws4[i] = W4[i];

  constexpr int AV = ROWS * (K / 4);
  for (int i = tid; i < AV; i += 256) {
    int r = i / (K / 4);
    int kk = i % (K / 4);
    float4 v = make_float4(0.f, 0.f, 0.f, 0.f);
    if (row0 + r < M) v = *(const float4*)&A[(size_t)(row0 + r) * K + kk * 4];
    *(float4*)&As[r * KP + kk * 4] = v;
  }
  __syncthreads();

  constexpr int CG = NCOL / 4;   // col groups of 4
  constexpr int RS = 256 / CG;   // row slots
  constexpr int NR = ROWS / RS;  // rows per thread
  int cg = tid % CG;
  int rslot = tid / CG;

  float4 acc[NR];
#pragma unroll
  for (int rr = 0; rr < NR; ++rr) acc[rr] = make_float4(0.f, 0.f, 0.f, 0.f);

  for (int k = 0; k < K; k += 4) {
    float4 w0 = *(const float4*)&Ws[(k + 0) * NCOL + cg * 4];
    float4 w1 = *(const float4*)&Ws[(k + 1) * NCOL + cg * 4];
    float4 w2 = *(const float4*)&Ws[(k + 2) * NCOL + cg * 4];
    float4 w3 = *(const float4*)&Ws[(k + 3) * NCOL + cg * 4];
#pragma unroll
    for (int rr = 0; rr < NR; ++rr) {
      int r = rslot * NR + rr;
      float4 a = *(const float4*)&As[r * KP + k];
      fma4(acc[rr], a.x, w0);
      fma4(acc[rr], a.y, w1);
      fma4(acc[rr], a.z, w2);
      fma4(acc[rr], a.w, w3);
    }
  }

#pragma unroll
  for (int rr = 0; rr < NR; ++rr) {
    int row = row0 + rslot * NR + rr;
    if (row < M) {
      float4 v = acc[rr];
      if (BIAS) {
        v.x += bias[cg * 4 + 0];
        v.y += bias[cg * 4 + 1];
        v.z += bias[cg * 4 + 2];
        v.w += bias[cg * 4 + 3];
      }
      *(float4*)&C[(size_t)row * NCOL + cg * 4] = v;
    }
  }
}

// Gather-based segment sum: out[n][f] = sum_{s in N(n)} hw[s][f]*dis[s]*dis[n]
//                                     + hw[n][f]*dis[n]^2  (+bias, opt relu)
template <int F, bool RELU>
__global__ __launch_bounds__(256) void gather_kernel(
    const float* __restrict__ hw, const float* __restrict__ dis,
    const int* __restrict__ off, const int* __restrict__ csr,
    const float* __restrict__ bias, float* __restrict__ out, int N) {
  constexpr int NPB = 256 / F;
  int local = threadIdx.x / F;
  int f = threadIdx.x % F;
  int n = blockIdx.x * NPB + local;
  if (n >= N) return;
  float dn = dis[n];
  float acc = hw[(size_t)n * F + f] * dn * dn;  // self loop
  int j0 = off[n];
  int j1 = off[n + 1];
  int j = j0;
  for (; j + 4 <= j1; j += 4) {
    int s0 = csr[j + 0];
    int s1 = csr[j + 1];
    int s2 = csr[j + 2];
    int s3 = csr[j + 3];
    float w0 = dis[s0] * dn;
    float w1 = dis[s1] * dn;
    float w2 = dis[s2] * dn;
    float w3 = dis[s3] * dn;
    float v0 = hw[(size_t)s0 * F + f];
    float v1 = hw[(size_t)s1 * F + f];
    float v2 = hw[(size_t)s2 * F + f];
    float v3 = hw[(size_t)s3 * F + f];
    acc = fmaf(v0, w0, acc);
    acc = fmaf(v1, w1, acc);
    acc = fmaf(v2, w2, acc);
    acc = fmaf(v3, w3, acc);
  }
  for (; j < j1; ++j) {
    int s = csr[j];
    acc = fmaf(hw[(size_t)s * F + f], dis[s] * dn, acc);
  }
  acc += bias[f];
  if (RELU) acc = fmaxf(acc, 0.f);
  out[(size_t)n * F + f] = acc;
}

extern "C" void kernel_launch(void* const* d_in, const int* in_sizes, int n_in,
                              void* d_out, int out_size, void* d_ws,
                              size_t ws_size, hipStream_t stream) {
  const float* x = (const float*)d_in[0];
  const int* ei = (const int*)d_in[1];
  const float* W1 = (const float*)d_in[2];
  const float* b1 = (const float*)d_in[3];
  const float* W2 = (const float*)d_in[4];
  const float* b2 = (const float*)d_in[5];
  const float* Wc = (const float*)d_in[6];
  const float* bc = (const float*)d_in[7];

  int N = in_sizes[0] / DIN;
  int E = in_sizes[1] / 2;

  char* w = (char*)d_ws;
  size_t off = 0;
  auto alloc = [&](size_t bytes) {
    char* p = w + off;
    off += (bytes + 255) & ~(size_t)255;
    return p;
  };
  int* counts = (int*)alloc((size_t)N * 4);
  int* offsets = (int*)alloc((size_t)(N + 1) * 4);
  int* cursor = (int*)alloc((size_t)N * 4);
  int* csr = (int*)alloc((size_t)E * 4);
  float* dis = (float*)alloc((size_t)N * 4);
  int* blockSums = (int*)alloc((size_t)1024 * 4);
  float* hw1 = (float*)alloc((size_t)N * DIN * 4);
  float* h1 = (float*)alloc((size_t)N * HID * 4);
  float* hw2 = hw1;  // alias: hw1 dead after gather1

  float* out_h2 = (float*)d_out;             // output 0: h2 [N x 64]
  float* out_y = out_h2 + (size_t)N * FOUT;  // output 1: out [N x 64]

  hipMemsetAsync(counts, 0, (size_t)N * 4, stream);

  int egrid = (E + 255) / 256;
  int ngrid = (N + 255) / 256;  // also the scan chunk count G
  int ggrid = (N + 31) / 32;

  hist_kernel<<<egrid, 256, 0, stream>>>(ei, E, counts);
  block_sum_kernel<<<ngrid, 256, 0, stream>>>(counts, N, blockSums);
  scan_blocksums_kernel<<<1, 1024, 0, stream>>>(blockSums, ngrid);
  scan_apply_kernel<<<ngrid, 256, 0, stream>>>(counts, blockSums, N, E,
                                               offsets, cursor, dis);
  fill_kernel<<<egrid, 256, 0, stream>>>(ei, E, cursor, csr);

  // layer 1: hw1 = x @ W1 ; h1 = relu(Agg(hw1) + b1)
  gemm_kernel<DIN, HID, false><<<ggrid, 256, 0, stream>>>(x, W1, nullptr, hw1, N);
  gather_kernel<HID, true><<<(N + 1) / 2, 256, 0, stream>>>(hw1, dis, offsets, csr, b1, h1, N);

  // layer 2: hw2 = h1 @ W2 ; h2 = Agg(hw2) + b2  -> d_out[0 : N*64]
  gemm_kernel<HID, FOUT, false><<<ggrid, 256, 0, stream>>>(h1, W2, nullptr, hw2, N);
  gather_kernel<FOUT, false><<<(N + 3) / 4, 256, 0, stream>>>(hw2, dis, offsets, csr, b2, out_h2, N);

  // head: out = h2 @ Wc + bc -> d_out[N*64 : 2*N*64]
  gemm_kernel<FOUT, FOUT, true><<<ggrid, 256, 0, stream>>>(out_h2, Wc, bc, out_y, N);
}

// Round 3
// 347.997 us; speedup vs baseline: 1.2686x; 1.0760x over previous
//
#include <hip/hip_runtime.h>

// GCN: h1 = relu(Agg(x@W1) + b1); h2 = Agg(h1@W2) + b2; out = h2@Wc + bc
// Agg = symmetric-normalized adjacency with self-loops (PyG GCNConv).
// CSR build: hist -> 3-level parallel scan (fused node_init) -> fill.
// Aggregation: one node per wave, float4 per lane, edge-slot parallel +
// shfl_xor fold (wave-uniform trip count, 64B gather bytes in flight/lane).

#define DIN 128
#define HID 128
#define FOUT 64

__global__ __launch_bounds__(256) void hist_kernel(
    const int* __restrict__ ei, int E, int* __restrict__ counts) {
  int e = blockIdx.x * 256 + threadIdx.x;
  if (e < E) atomicAdd(&counts[ei[E + e]], 1);
}

// Level 1: per-block sums of 256-count chunks.
__global__ __launch_bounds__(256) void block_sum_kernel(
    const int* __restrict__ counts, int N, int* __restrict__ blockSums) {
  int i = blockIdx.x * 256 + threadIdx.x;
  int v = (i < N) ? counts[i] : 0;
#pragma unroll
  for (int off = 32; off > 0; off >>= 1) v += __shfl_down(v, off, 64);
  __shared__ int ws[4];
  if ((threadIdx.x & 63) == 0) ws[threadIdx.x >> 6] = v;
  __syncthreads();
  if (threadIdx.x == 0)
    blockSums[blockIdx.x] = ws[0] + ws[1] + ws[2] + ws[3];
}

// Level 2: single-block exclusive scan of up to 1024 block sums.
__global__ __launch_bounds__(1024) void scan_blocksums_kernel(
    int* __restrict__ blockSums, int G) {
  __shared__ int s[1024];
  int t = threadIdx.x;
  int v = (t < G) ? blockSums[t] : 0;
  s[t] = v;
  __syncthreads();
  for (int off = 1; off < 1024; off <<= 1) {
    int u = 0;
    if (t >= off) u = s[t - off];
    __syncthreads();
    s[t] += u;
    __syncthreads();
  }
  if (t < G) blockSums[t] = s[t] - v;  // exclusive
}

// Level 3: re-scan chunk, add block offset; fused node_init (dis, cursor).
__global__ __launch_bounds__(256) void scan_apply_kernel(
    const int* __restrict__ counts, const int* __restrict__ blockSums, int N,
    int E, int* __restrict__ offsets, int* __restrict__ cursor,
    float* __restrict__ dis) {
  int t = threadIdx.x;
  int i = blockIdx.x * 256 + t;
  int c = (i < N) ? counts[i] : 0;
  __shared__ int s[256];
  s[t] = c;
  __syncthreads();
  for (int off = 1; off < 256; off <<= 1) {
    int u = 0;
    if (t >= off) u = s[t - off];
    __syncthreads();
    s[t] += u;
    __syncthreads();
  }
  int excl = s[t] - c + blockSums[blockIdx.x];
  if (i < N) {
    offsets[i] = excl;
    cursor[i] = excl;
    dis[i] = rsqrtf((float)c + 1.0f);  // deg includes self-loop
  }
  if (i == N - 1) offsets[N] = E;
}

__global__ __launch_bounds__(256) void fill_kernel(
    const int* __restrict__ ei, int E, int* __restrict__ cursor,
    int* __restrict__ csr) {
  int e = blockIdx.x * 256 + threadIdx.x;
  if (e < E) {
    int s = ei[e];
    int d = ei[E + e];
    int p = atomicAdd(&cursor[d], 1);
    csr[p] = s;
  }
}

__device__ inline void fma4(float4& c, float a, const float4& w) {
  c.x = fmaf(a, w.x, c.x);
  c.y = fmaf(a, w.y, c.y);
  c.z = fmaf(a, w.z, c.z);
  c.w = fmaf(a, w.w, c.w);
}

// C[M x NCOL] = A[M x K] @ W[K x NCOL] (+bias). W staged in LDS, A tile in LDS.
template <int K, int NCOL, bool BIAS>
__global__ __launch_bounds__(256) void gemm_kernel(
    const float* __restrict__ A, const float* __restrict__ W,
    const float* __restrict__ bias, float* __restrict__ C, int M) {
  constexpr int ROWS = 32;
  constexpr int KP = (NCOL == 128) ? K : (K + 4);
  __shared__ __align__(16) float Ws[K * NCOL];
  __shared__ __align__(16) float As[ROWS * KP];
  int tid = threadIdx.x;
  int row0 = blockIdx.x * ROWS;

  const float4* W4 = (const float4*)W;
  float4* Ws4 = (float4*)Ws;
  constexpr int WV = K * NCOL / 4;
  for (int i = tid; i < WV; i += 256) Ws4[i] = W4[i];

  constexpr int AV = ROWS * (K / 4);
  for (int i = tid; i < AV; i += 256) {
    int r = i / (K / 4);
    int kk = i % (K / 4);
    float4 v = make_float4(0.f, 0.f, 0.f, 0.f);
    if (row0 + r < M) v = *(const float4*)&A[(size_t)(row0 + r) * K + kk * 4];
    *(float4*)&As[r * KP + kk * 4] = v;
  }
  __syncthreads();

  constexpr int CG = NCOL / 4;   // col groups of 4
  constexpr int RS = 256 / CG;   // row slots
  constexpr int NR = ROWS / RS;  // rows per thread
  int cg = tid % CG;
  int rslot = tid / CG;

  float4 acc[NR];
#pragma unroll
  for (int rr = 0; rr < NR; ++rr) acc[rr] = make_float4(0.f, 0.f, 0.f, 0.f);

  for (int k = 0; k < K; k += 4) {
    float4 w0 = *(const float4*)&Ws[(k + 0) * NCOL + cg * 4];
    float4 w1 = *(const float4*)&Ws[(k + 1) * NCOL + cg * 4];
    float4 w2 = *(const float4*)&Ws[(k + 2) * NCOL + cg * 4];
    float4 w3 = *(const float4*)&Ws[(k + 3) * NCOL + cg * 4];
#pragma unroll
    for (int rr = 0; rr < NR; ++rr) {
      int r = rslot * NR + rr;
      float4 a = *(const float4*)&As[r * KP + k];
      fma4(acc[rr], a.x, w0);
      fma4(acc[rr], a.y, w1);
      fma4(acc[rr], a.z, w2);
      fma4(acc[rr], a.w, w3);
    }
  }

#pragma unroll
  for (int rr = 0; rr < NR; ++rr) {
    int row = row0 + rslot * NR + rr;
    if (row < M) {
      float4 v = acc[rr];
      if (BIAS) {
        v.x += bias[cg * 4 + 0];
        v.y += bias[cg * 4 + 1];
        v.z += bias[cg * 4 + 2];
        v.w += bias[cg * 4 + 3];
      }
      *(float4*)&C[(size_t)row * NCOL + cg * 4] = v;
    }
  }
}

// Gather segment-sum, one node per 64-lane wave.
// Lanes = EPW edge-slots x FQ float4 feature chunks. Wave-uniform trip count.
// out[n][:] = sum_{s in N(n)} hw[s][:]*dis[s]*dis[n] + hw[n][:]*dis[n]^2
//             (+bias, opt relu)
template <int F, bool RELU>
__global__ __launch_bounds__(256) void gather_kernel(
    const float* __restrict__ hw, const float* __restrict__ dis,
    const int* __restrict__ off, const int* __restrict__ csr,
    const float* __restrict__ bias, float* __restrict__ out, int N) {
  constexpr int FQ = F / 4;     // float4 chunks per row (32 or 16)
  constexpr int EPW = 64 / FQ;  // edge slots per wave (2 or 4)
  int wave = threadIdx.x >> 6;
  int lane = threadIdx.x & 63;
  int eslot = lane / FQ;
  int f4 = lane % FQ;
  int n = blockIdx.x * 4 + wave;
  if (n >= N) return;

  const float4* hw4 = (const float4*)hw;
  float dn = dis[n];
  float4 acc = make_float4(0.f, 0.f, 0.f, 0.f);
  if (eslot == 0) {  // self loop
    float4 v = hw4[(size_t)n * FQ + f4];
    float wgt = dn * dn;
    acc.x = v.x * wgt;
    acc.y = v.y * wgt;
    acc.z = v.z * wgt;
    acc.w = v.w * wgt;
  }

  int j0 = off[n], j1 = off[n + 1];
  int j = j0 + eslot;
  // 4-deep unroll: 4 gather float4s in flight per lane (64B MLP/lane)
  for (; j + 3 * EPW < j1; j += 4 * EPW) {
    int s0 = csr[j + 0 * EPW];
    int s1 = csr[j + 1 * EPW];
    int s2 = csr[j + 2 * EPW];
    int s3 = csr[j + 3 * EPW];
    float w0 = dis[s0] * dn;
    float w1 = dis[s1] * dn;
    float w2 = dis[s2] * dn;
    float w3 = dis[s3] * dn;
    float4 v0 = hw4[(size_t)s0 * FQ + f4];
    float4 v1 = hw4[(size_t)s1 * FQ + f4];
    float4 v2 = hw4[(size_t)s2 * FQ + f4];
    float4 v3 = hw4[(size_t)s3 * FQ + f4];
    fma4(acc, w0, v0);
    fma4(acc, w1, v1);
    fma4(acc, w2, v2);
    fma4(acc, w3, v3);
  }
  for (; j < j1; j += EPW) {
    int s = csr[j];
    float wgt = dis[s] * dn;
    float4 v = hw4[(size_t)s * FQ + f4];
    fma4(acc, wgt, v);
  }

  // fold edge slots: strides FQ..32
#pragma unroll
  for (int st = FQ; st < 64; st <<= 1) {
    acc.x += __shfl_xor(acc.x, st, 64);
    acc.y += __shfl_xor(acc.y, st, 64);
    acc.z += __shfl_xor(acc.z, st, 64);
    acc.w += __shfl_xor(acc.w, st, 64);
  }

  if (eslot == 0) {
    float4 b = ((const float4*)bias)[f4];
    acc.x += b.x;
    acc.y += b.y;
    acc.z += b.z;
    acc.w += b.w;
    if (RELU) {
      acc.x = fmaxf(acc.x, 0.f);
      acc.y = fmaxf(acc.y, 0.f);
      acc.z = fmaxf(acc.z, 0.f);
      acc.w = fmaxf(acc.w, 0.f);
    }
    ((float4*)out)[(size_t)n * FQ + f4] = acc;
  }
}

extern "C" void kernel_launch(void* const* d_in, const int* in_sizes, int n_in,
                              void* d_out, int out_size, void* d_ws,
                              size_t ws_size, hipStream_t stream) {
  const float* x = (const float*)d_in[0];
  const int* ei = (const int*)d_in[1];
  const float* W1 = (const float*)d_in[2];
  const float* b1 = (const float*)d_in[3];
  const float* W2 = (const float*)d_in[4];
  const float* b2 = (const float*)d_in[5];
  const float* Wc = (const float*)d_in[6];
  const float* bc = (const float*)d_in[7];

  int N = in_sizes[0] / DIN;
  int E = in_sizes[1] / 2;

  char* w = (char*)d_ws;
  size_t off = 0;
  auto alloc = [&](size_t bytes) {
    char* p = w + off;
    off += (bytes + 255) & ~(size_t)255;
    return p;
  };
  int* counts = (int*)alloc((size_t)N * 4);
  int* offsets = (int*)alloc((size_t)(N + 1) * 4);
  int* cursor = (int*)alloc((size_t)N * 4);
  int* csr = (int*)alloc((size_t)E * 4);
  float* dis = (float*)alloc((size_t)N * 4);
  int* blockSums = (int*)alloc((size_t)1024 * 4);
  float* hw1 = (float*)alloc((size_t)N * DIN * 4);
  float* h1 = (float*)alloc((size_t)N * HID * 4);
  float* hw2 = hw1;  // alias: hw1 dead after gather1

  float* out_h2 = (float*)d_out;             // output 0: h2 [N x 64]
  float* out_y = out_h2 + (size_t)N * FOUT;  // output 1: out [N x 64]

  hipMemsetAsync(counts, 0, (size_t)N * 4, stream);

  int egrid = (E + 255) / 256;
  int ngrid = (N + 255) / 256;  // scan chunk count G
  int ggrid = (N + 31) / 32;
  int wgrid = (N + 3) / 4;  // gather: 4 nodes (waves) per block

  hist_kernel<<<egrid, 256, 0, stream>>>(ei, E, counts);
  block_sum_kernel<<<ngrid, 256, 0, stream>>>(counts, N, blockSums);
  scan_blocksums_kernel<<<1, 1024, 0, stream>>>(blockSums, ngrid);
  scan_apply_kernel<<<ngrid, 256, 0, stream>>>(counts, blockSums, N, E,
                                               offsets, cursor, dis);
  fill_kernel<<<egrid, 256, 0, stream>>>(ei, E, cursor, csr);

  // layer 1: hw1 = x @ W1 ; h1 = relu(Agg(hw1) + b1)
  gemm_kernel<DIN, HID, false><<<ggrid, 256, 0, stream>>>(x, W1, nullptr, hw1, N);
  gather_kernel<HID, true><<<wgrid, 256, 0, stream>>>(hw1, dis, offsets, csr, b1, h1, N);

  // layer 2: hw2 = h1 @ W2 ; h2 = Agg(hw2) + b2  -> d_out[0 : N*64]
  gemm_kernel<HID, FOUT, false><<<ggrid, 256, 0, stream>>>(h1, W2, nullptr, hw2, N);
  gather_kernel<FOUT, false><<<wgrid, 256, 0, stream>>>(hw2, dis, offsets, csr, b2, out_h2, N);

  // head: out = h2 @ Wc + bc -> d_out[N*64 : 2*N*64]
  gemm_kernel<FOUT, FOUT, true><<<ggrid, 256, 0, stream>>>(out_h2, Wc, bc, out_y, N);
}

// Round 4
// 328.765 us; speedup vs baseline: 1.3428x; 1.0585x over previous
//
#include <hip/hip_runtime.h>

// GCN: h1 = relu(Agg(x@W1) + b1); h2 = Agg(h1@W2) + b2; out = h2@Wc + bc
// Agg = symmetric-normalized adjacency with self-loops (PyG GCNConv).
// CSR build: hist -> 3-level parallel scan (fused node_init) -> fill.
// Gather operand stored as fp16 pre-scaled by dis[src] (gemm epilogue):
// halves L2-miss gather traffic and removes per-edge dis load; gather is a
// pure fp32-accumulated sum, one node per wave, 16B/lane loads.

#define DIN 128
#define HID 128
#define FOUT 64

using half4 = __attribute__((ext_vector_type(4))) _Float16;
using half8 = __attribute__((ext_vector_type(8))) _Float16;
using float8 = __attribute__((ext_vector_type(8))) float;

__global__ __launch_bounds__(256) void hist_kernel(
    const int* __restrict__ ei, int E, int* __restrict__ counts) {
  int e = blockIdx.x * 256 + threadIdx.x;
  if (e < E) atomicAdd(&counts[ei[E + e]], 1);
}

// Level 1: per-block sums of 256-count chunks.
__global__ __launch_bounds__(256) void block_sum_kernel(
    const int* __restrict__ counts, int N, int* __restrict__ blockSums) {
  int i = blockIdx.x * 256 + threadIdx.x;
  int v = (i < N) ? counts[i] : 0;
#pragma unroll
  for (int off = 32; off > 0; off >>= 1) v += __shfl_down(v, off, 64);
  __shared__ int ws[4];
  if ((threadIdx.x & 63) == 0) ws[threadIdx.x >> 6] = v;
  __syncthreads();
  if (threadIdx.x == 0)
    blockSums[blockIdx.x] = ws[0] + ws[1] + ws[2] + ws[3];
}

// Level 2: single-block exclusive scan of up to 1024 block sums.
__global__ __launch_bounds__(1024) void scan_blocksums_kernel(
    int* __restrict__ blockSums, int G) {
  __shared__ int s[1024];
  int t = threadIdx.x;
  int v = (t < G) ? blockSums[t] : 0;
  s[t] = v;
  __syncthreads();
  for (int off = 1; off < 1024; off <<= 1) {
    int u = 0;
    if (t >= off) u = s[t - off];
    __syncthreads();
    s[t] += u;
    __syncthreads();
  }
  if (t < G) blockSums[t] = s[t] - v;  // exclusive
}

// Level 3: re-scan chunk, add block offset; fused node_init (dis, cursor).
__global__ __launch_bounds__(256) void scan_apply_kernel(
    const int* __restrict__ counts, const int* __restrict__ blockSums, int N,
    int E, int* __restrict__ offsets, int* __restrict__ cursor,
    float* __restrict__ dis) {
  int t = threadIdx.x;
  int i = blockIdx.x * 256 + t;
  int c = (i < N) ? counts[i] : 0;
  __shared__ int s[256];
  s[t] = c;
  __syncthreads();
  for (int off = 1; off < 256; off <<= 1) {
    int u = 0;
    if (t >= off) u = s[t - off];
    __syncthreads();
    s[t] += u;
    __syncthreads();
  }
  int excl = s[t] - c + blockSums[blockIdx.x];
  if (i < N) {
    offsets[i] = excl;
    cursor[i] = excl;
    dis[i] = rsqrtf((float)c + 1.0f);  // deg includes self-loop
  }
  if (i == N - 1) offsets[N] = E;
}

__global__ __launch_bounds__(256) void fill_kernel(
    const int* __restrict__ ei, int E, int* __restrict__ cursor,
    int* __restrict__ csr) {
  int e = blockIdx.x * 256 + threadIdx.x;
  if (e < E) {
    int s = ei[e];
    int d = ei[E + e];
    int p = atomicAdd(&cursor[d], 1);
    csr[p] = s;
  }
}

__device__ inline void fma4(float4& c, float a, const float4& w) {
  c.x = fmaf(a, w.x, c.x);
  c.y = fmaf(a, w.y, c.y);
  c.z = fmaf(a, w.z, c.z);
  c.w = fmaf(a, w.w, c.w);
}

// C[M x NCOL] = A[M x K] @ W[K x NCOL].
// HOUT: store fp16 scaled by dis[row] (gather operand). Else fp32 (+bias).
template <int K, int NCOL, bool BIAS, bool HOUT>
__global__ __launch_bounds__(256) void gemm_kernel(
    const float* __restrict__ A, const float* __restrict__ W,
    const float* __restrict__ bias, const float* __restrict__ dis,
    void* __restrict__ Cout, int M) {
  constexpr int ROWS = 32;
  constexpr int KP = (NCOL == 128) ? K : (K + 4);
  __shared__ __align__(16) float Ws[K * NCOL];
  __shared__ __align__(16) float As[ROWS * KP];
  int tid = threadIdx.x;
  int row0 = blockIdx.x * ROWS;

  const float4* W4 = (const float4*)W;
  float4* Ws4 = (float4*)Ws;
  constexpr int WV = K * NCOL / 4;
  for (int i = tid; i < WV; i += 256) Ws4[i] = W4[i];

  constexpr int AV = ROWS * (K / 4);
  for (int i = tid; i < AV; i += 256) {
    int r = i / (K / 4);
    int kk = i % (K / 4);
    float4 v = make_float4(0.f, 0.f, 0.f, 0.f);
    if (row0 + r < M) v = *(const float4*)&A[(size_t)(row0 + r) * K + kk * 4];
    *(float4*)&As[r * KP + kk * 4] = v;
  }
  __syncthreads();

  constexpr int CG = NCOL / 4;   // col groups of 4
  constexpr int RS = 256 / CG;   // row slots
  constexpr int NR = ROWS / RS;  // rows per thread
  int cg = tid % CG;
  int rslot = tid / CG;

  float4 acc[NR];
#pragma unroll
  for (int rr = 0; rr < NR; ++rr) acc[rr] = make_float4(0.f, 0.f, 0.f, 0.f);

  for (int k = 0; k < K; k += 4) {
    float4 w0 = *(const float4*)&Ws[(k + 0) * NCOL + cg * 4];
    float4 w1 = *(const float4*)&Ws[(k + 1) * NCOL + cg * 4];
    float4 w2 = *(const float4*)&Ws[(k + 2) * NCOL + cg * 4];
    float4 w3 = *(const float4*)&Ws[(k + 3) * NCOL + cg * 4];
#pragma unroll
    for (int rr = 0; rr < NR; ++rr) {
      int r = rslot * NR + rr;
      float4 a = *(const float4*)&As[r * KP + k];
      fma4(acc[rr], a.x, w0);
      fma4(acc[rr], a.y, w1);
      fma4(acc[rr], a.z, w2);
      fma4(acc[rr], a.w, w3);
    }
  }

#pragma unroll
  for (int rr = 0; rr < NR; ++rr) {
    int row = row0 + rslot * NR + rr;
    if (row < M) {
      float4 v = acc[rr];
      if (HOUT) {
        float d = dis[row];
        half4 h;
        h[0] = (_Float16)(v.x * d);
        h[1] = (_Float16)(v.y * d);
        h[2] = (_Float16)(v.z * d);
        h[3] = (_Float16)(v.w * d);
        *(half4*)((_Float16*)Cout + (size_t)row * NCOL + cg * 4) = h;
      } else {
        if (BIAS) {
          v.x += bias[cg * 4 + 0];
          v.y += bias[cg * 4 + 1];
          v.z += bias[cg * 4 + 2];
          v.w += bias[cg * 4 + 3];
        }
        *(float4*)((float*)Cout + (size_t)row * NCOL + cg * 4) = v;
      }
    }
  }
}

// Gather segment-sum over pre-scaled fp16 rows, one node per 64-lane wave.
// Lanes = EPW edge-slots x FC half8 feature chunks (16B/lane loads).
// out[n][:] = dis[n] * (sum_{s in N(n)} hws[s][:] + hws[n][:]) + bias
// where hws[r] = (h@W)[r] * dis[r] (done in gemm epilogue). fp32 accumulate.
template <int F, bool RELU>
__global__ __launch_bounds__(256) void gather_kernel(
    const _Float16* __restrict__ hw, const float* __restrict__ dis,
    const int* __restrict__ off, const int* __restrict__ csr,
    const float* __restrict__ bias, float* __restrict__ out, int N) {
  constexpr int FC = F / 8;     // half8 chunks per row (16 or 8)
  constexpr int EPW = 64 / FC;  // edge slots per wave (4 or 8)
  int wave = threadIdx.x >> 6;
  int lane = threadIdx.x & 63;
  int eslot = lane / FC;
  int c = lane % FC;
  int n = blockIdx.x * 4 + wave;
  if (n >= N) return;

  const half8* hw8 = (const half8*)hw;
  float8 acc = {0.f, 0.f, 0.f, 0.f, 0.f, 0.f, 0.f, 0.f};
  if (eslot == 0)  // self loop (pre-scaled row, final *dn below)
    acc = __builtin_convertvector(hw8[(size_t)n * FC + c], float8);

  int j0 = off[n], j1 = off[n + 1];
  int j = j0 + eslot;
  // 4-deep unroll: 4 x 16B gathers in flight per lane
  for (; j + 3 * EPW < j1; j += 4 * EPW) {
    int s0 = csr[j + 0 * EPW];
    int s1 = csr[j + 1 * EPW];
    int s2 = csr[j + 2 * EPW];
    int s3 = csr[j + 3 * EPW];
    half8 v0 = hw8[(size_t)s0 * FC + c];
    half8 v1 = hw8[(size_t)s1 * FC + c];
    half8 v2 = hw8[(size_t)s2 * FC + c];
    half8 v3 = hw8[(size_t)s3 * FC + c];
    acc += __builtin_convertvector(v0, float8);
    acc += __builtin_convertvector(v1, float8);
    acc += __builtin_convertvector(v2, float8);
    acc += __builtin_convertvector(v3, float8);
  }
  for (; j < j1; j += EPW)
    acc += __builtin_convertvector(hw8[(size_t)csr[j] * FC + c], float8);

  // fold edge slots
#pragma unroll
  for (int st = FC; st < 64; st <<= 1) {
#pragma unroll
    for (int i = 0; i < 8; ++i) acc[i] += __shfl_xor(acc[i], st, 64);
  }

  if (eslot == 0) {
    float dn = dis[n];
    float4 b0 = *(const float4*)&bias[c * 8 + 0];
    float4 b1 = *(const float4*)&bias[c * 8 + 4];
    float4 r0 = make_float4(fmaf(acc[0], dn, b0.x), fmaf(acc[1], dn, b0.y),
                            fmaf(acc[2], dn, b0.z), fmaf(acc[3], dn, b0.w));
    float4 r1 = make_float4(fmaf(acc[4], dn, b1.x), fmaf(acc[5], dn, b1.y),
                            fmaf(acc[6], dn, b1.z), fmaf(acc[7], dn, b1.w));
    if (RELU) {
      r0.x = fmaxf(r0.x, 0.f); r0.y = fmaxf(r0.y, 0.f);
      r0.z = fmaxf(r0.z, 0.f); r0.w = fmaxf(r0.w, 0.f);
      r1.x = fmaxf(r1.x, 0.f); r1.y = fmaxf(r1.y, 0.f);
      r1.z = fmaxf(r1.z, 0.f); r1.w = fmaxf(r1.w, 0.f);
    }
    float* op = out + (size_t)n * F + c * 8;
    *(float4*)(op + 0) = r0;
    *(float4*)(op + 4) = r1;
  }
}

extern "C" void kernel_launch(void* const* d_in, const int* in_sizes, int n_in,
                              void* d_out, int out_size, void* d_ws,
                              size_t ws_size, hipStream_t stream) {
  const float* x = (const float*)d_in[0];
  const int* ei = (const int*)d_in[1];
  const float* W1 = (const float*)d_in[2];
  const float* b1 = (const float*)d_in[3];
  const float* W2 = (const float*)d_in[4];
  const float* b2 = (const float*)d_in[5];
  const float* Wc = (const float*)d_in[6];
  const float* bc = (const float*)d_in[7];

  int N = in_sizes[0] / DIN;
  int E = in_sizes[1] / 2;

  char* w = (char*)d_ws;
  size_t off = 0;
  auto alloc = [&](size_t bytes) {
    char* p = w + off;
    off += (bytes + 255) & ~(size_t)255;
    return p;
  };
  int* counts = (int*)alloc((size_t)N * 4);
  int* offsets = (int*)alloc((size_t)(N + 1) * 4);
  int* cursor = (int*)alloc((size_t)N * 4);
  int* csr = (int*)alloc((size_t)E * 4);
  float* dis = (float*)alloc((size_t)N * 4);
  int* blockSums = (int*)alloc((size_t)1024 * 4);
  _Float16* hw1 = (_Float16*)alloc((size_t)N * DIN * 2);  // fp16, dis-scaled
  float* h1 = (float*)alloc((size_t)N * HID * 4);
  _Float16* hw2 = hw1;  // alias: hw1 dead after gather1

  float* out_h2 = (float*)d_out;             // output 0: h2 [N x 64]
  float* out_y = out_h2 + (size_t)N * FOUT;  // output 1: out [N x 64]

  hipMemsetAsync(counts, 0, (size_t)N * 4, stream);

  int egrid = (E + 255) / 256;
  int ngrid = (N + 255) / 256;  // scan chunk count G
  int ggrid = (N + 31) / 32;
  int wgrid = (N + 3) / 4;  // gather: 4 nodes (waves) per block

  hist_kernel<<<egrid, 256, 0, stream>>>(ei, E, counts);
  block_sum_kernel<<<ngrid, 256, 0, stream>>>(counts, N, blockSums);
  scan_blocksums_kernel<<<1, 1024, 0, stream>>>(blockSums, ngrid);
  scan_apply_kernel<<<ngrid, 256, 0, stream>>>(counts, blockSums, N, E,
                                               offsets, cursor, dis);
  fill_kernel<<<egrid, 256, 0, stream>>>(ei, E, cursor, csr);

  // layer 1: hw1 = (x @ W1)*dis (fp16) ; h1 = relu(dn*Agg(hw1) + b1)
  gemm_kernel<DIN, HID, false, true><<<ggrid, 256, 0, stream>>>(
      x, W1, nullptr, dis, hw1, N);
  gather_kernel<HID, true><<<wgrid, 256, 0, stream>>>(hw1, dis, offsets, csr,
                                                      b1, h1, N);

  // layer 2: hw2 = (h1 @ W2)*dis (fp16) ; h2 = dn*Agg(hw2) + b2 -> d_out[0:]
  gemm_kernel<HID, FOUT, false, true><<<ggrid, 256, 0, stream>>>(
      h1, W2, nullptr, dis, hw2, N);
  gather_kernel<FOUT, false><<<wgrid, 256, 0, stream>>>(hw2, dis, offsets, csr,
                                                        b2, out_h2, N);

  // head: out = h2 @ Wc + bc -> d_out[N*64 : 2*N*64]
  gemm_kernel<FOUT, FOUT, true, false><<<ggrid, 256, 0, stream>>>(
      out_h2, Wc, bc, nullptr, out_y, N);
}

// Round 5
// 310.707 us; speedup vs baseline: 1.4208x; 1.0581x over previous
//
#include <hip/hip_runtime.h>

// GCN: h1 = relu(Agg(x@W1) + b1); h2 = Agg(h1@W2) + b2; out = h2@Wc + bc
// Agg = symmetric-normalized adjacency with self-loops (PyG GCNConv).
// CSR build: XCD-partitioned hist -> 3-level scan (fused node_init) ->
// XCD-partitioned fill (dst-range partition = blockIdx&7 so each csr/cursor
// line is owned by one XCD L2: kills 64B/4B write amplification + atomic
// line bounce seen in R4: WRITE_SIZE was E*64B).
// Gather: fp16 rows pre-scaled by dis[src] (gemm epilogue), one node per
// wave, 16B/lane loads, fp32 accumulate.

#define DIN 128
#define HID 128
#define FOUT 64

using half4 = __attribute__((ext_vector_type(4))) _Float16;
using half8 = __attribute__((ext_vector_type(8))) _Float16;
using float8 = __attribute__((ext_vector_type(8))) float;

// Deterministic dst->partition map (pure function; locality heuristic only).
__device__ inline int part_of(int d, float invn) {
  int p = (int)((float)d * invn);
  return p > 7 ? 7 : p;
}

// Partitioned histogram: block b = chunk (b>>3) x partition (b&7).
__global__ __launch_bounds__(256) void hist_kernel(
    const int* __restrict__ ei, int E, int* __restrict__ counts, float invn) {
  int part = blockIdx.x & 7;
  int e = (blockIdx.x >> 3) * 256 + threadIdx.x;
  if (e >= E) return;
  int d = ei[E + e];
  if (part_of(d, invn) == part) atomicAdd(&counts[d], 1);
}

// Level 1: per-block sums of 256-count chunks.
__global__ __launch_bounds__(256) void block_sum_kernel(
    const int* __restrict__ counts, int N, int* __restrict__ blockSums) {
  int i = blockIdx.x * 256 + threadIdx.x;
  int v = (i < N) ? counts[i] : 0;
#pragma unroll
  for (int off = 32; off > 0; off >>= 1) v += __shfl_down(v, off, 64);
  __shared__ int ws[4];
  if ((threadIdx.x & 63) == 0) ws[threadIdx.x >> 6] = v;
  __syncthreads();
  if (threadIdx.x == 0)
    blockSums[blockIdx.x] = ws[0] + ws[1] + ws[2] + ws[3];
}

// Level 2: single-block exclusive scan of up to 1024 block sums.
__global__ __launch_bounds__(1024) void scan_blocksums_kernel(
    int* __restrict__ blockSums, int G) {
  __shared__ int s[1024];
  int t = threadIdx.x;
  int v = (t < G) ? blockSums[t] : 0;
  s[t] = v;
  __syncthreads();
  for (int off = 1; off < 1024; off <<= 1) {
    int u = 0;
    if (t >= off) u = s[t - off];
    __syncthreads();
    s[t] += u;
    __syncthreads();
  }
  if (t < G) blockSums[t] = s[t] - v;  // exclusive
}

// Level 3: re-scan chunk, add block offset; fused node_init (dis, cursor).
__global__ __launch_bounds__(256) void scan_apply_kernel(
    const int* __restrict__ counts, const int* __restrict__ blockSums, int N,
    int E, int* __restrict__ offsets, int* __restrict__ cursor,
    float* __restrict__ dis) {
  int t = threadIdx.x;
  int i = blockIdx.x * 256 + t;
  int c = (i < N) ? counts[i] : 0;
  __shared__ int s[256];
  s[t] = c;
  __syncthreads();
  for (int off = 1; off < 256; off <<= 1) {
    int u = 0;
    if (t >= off) u = s[t - off];
    __syncthreads();
    s[t] += u;
    __syncthreads();
  }
  int excl = s[t] - c + blockSums[blockIdx.x];
  if (i < N) {
    offsets[i] = excl;
    cursor[i] = excl;
    dis[i] = rsqrtf((float)c + 1.0f);  // deg includes self-loop
  }
  if (i == N - 1) offsets[N] = E;
}

// Partitioned fill: only XCD (blockIdx&7) writes partition's csr/cursor range.
__global__ __launch_bounds__(256) void fill_kernel(
    const int* __restrict__ ei, int E, int* __restrict__ cursor,
    int* __restrict__ csr, float invn) {
  int part = blockIdx.x & 7;
  int e = (blockIdx.x >> 3) * 256 + threadIdx.x;
  if (e >= E) return;
  int d = ei[E + e];
  if (part_of(d, invn) != part) return;
  int s = ei[e];
  int p = atomicAdd(&cursor[d], 1);
  csr[p] = s;
}

__device__ inline void fma4(float4& c, float a, const float4& w) {
  c.x = fmaf(a, w.x, c.x);
  c.y = fmaf(a, w.y, c.y);
  c.z = fmaf(a, w.z, c.z);
  c.w = fmaf(a, w.w, c.w);
}

// C[M x NCOL] = A[M x K] @ W[K x NCOL].
// HOUT: store fp16 scaled by dis[row] (gather operand). Else fp32 (+bias).
template <int K, int NCOL, bool BIAS, bool HOUT>
__global__ __launch_bounds__(256) void gemm_kernel(
    const float* __restrict__ A, const float* __restrict__ W,
    const float* __restrict__ bias, const float* __restrict__ dis,
    void* __restrict__ Cout, int M) {
  constexpr int ROWS = 32;
  constexpr int KP = (NCOL == 128) ? K : (K + 4);
  __shared__ __align__(16) float Ws[K * NCOL];
  __shared__ __align__(16) float As[ROWS * KP];
  int tid = threadIdx.x;
  int row0 = blockIdx.x * ROWS;

  const float4* W4 = (const float4*)W;
  float4* Ws4 = (float4*)Ws;
  constexpr int WV = K * NCOL / 4;
  for (int i = tid; i < WV; i += 256) Ws4[i] = W4[i];

  constexpr int AV = ROWS * (K / 4);
  for (int i = tid; i < AV; i += 256) {
    int r = i / (K / 4);
    int kk = i % (K / 4);
    float4 v = make_float4(0.f, 0.f, 0.f, 0.f);
    if (row0 + r < M) v = *(const float4*)&A[(size_t)(row0 + r) * K + kk * 4];
    *(float4*)&As[r * KP + kk * 4] = v;
  }
  __syncthreads();

  constexpr int CG = NCOL / 4;   // col groups of 4
  constexpr int RS = 256 / CG;   // row slots
  constexpr int NR = ROWS / RS;  // rows per thread
  int cg = tid % CG;
  int rslot = tid / CG;

  float4 acc[NR];
#pragma unroll
  for (int rr = 0; rr < NR; ++rr) acc[rr] = make_float4(0.f, 0.f, 0.f, 0.f);

  for (int k = 0; k < K; k += 4) {
    float4 w0 = *(const float4*)&Ws[(k + 0) * NCOL + cg * 4];
    float4 w1 = *(const float4*)&Ws[(k + 1) * NCOL + cg * 4];
    float4 w2 = *(const float4*)&Ws[(k + 2) * NCOL + cg * 4];
    float4 w3 = *(const float4*)&Ws[(k + 3) * NCOL + cg * 4];
#pragma unroll
    for (int rr = 0; rr < NR; ++rr) {
      int r = rslot * NR + rr;
      float4 a = *(const float4*)&As[r * KP + k];
      fma4(acc[rr], a.x, w0);
      fma4(acc[rr], a.y, w1);
      fma4(acc[rr], a.z, w2);
      fma4(acc[rr], a.w, w3);
    }
  }

#pragma unroll
  for (int rr = 0; rr < NR; ++rr) {
    int row = row0 + rslot * NR + rr;
    if (row < M) {
      float4 v = acc[rr];
      if (HOUT) {
        float d = dis[row];
        half4 h;
        h[0] = (_Float16)(v.x * d);
        h[1] = (_Float16)(v.y * d);
        h[2] = (_Float16)(v.z * d);
        h[3] = (_Float16)(v.w * d);
        *(half4*)((_Float16*)Cout + (size_t)row * NCOL + cg * 4) = h;
      } else {
        if (BIAS) {
          v.x += bias[cg * 4 + 0];
          v.y += bias[cg * 4 + 1];
          v.z += bias[cg * 4 + 2];
          v.w += bias[cg * 4 + 3];
        }
        *(float4*)((float*)Cout + (size_t)row * NCOL + cg * 4) = v;
      }
    }
  }
}

// Gather segment-sum over pre-scaled fp16 rows, one node per 64-lane wave.
// Lanes = EPW edge-slots x FC half8 feature chunks (16B/lane loads).
// out[n][:] = dis[n] * (sum_{s in N(n)} hws[s][:] + hws[n][:]) + bias
// where hws[r] = (h@W)[r] * dis[r] (done in gemm epilogue). fp32 accumulate.
template <int F, bool RELU>
__global__ __launch_bounds__(256) void gather_kernel(
    const _Float16* __restrict__ hw, const float* __restrict__ dis,
    const int* __restrict__ off, const int* __restrict__ csr,
    const float* __restrict__ bias, float* __restrict__ out, int N) {
  constexpr int FC = F / 8;     // half8 chunks per row (16 or 8)
  constexpr int EPW = 64 / FC;  // edge slots per wave (4 or 8)
  int wave = threadIdx.x >> 6;
  int lane = threadIdx.x & 63;
  int eslot = lane / FC;
  int c = lane % FC;
  int n = blockIdx.x * 4 + wave;
  if (n >= N) return;

  const half8* hw8 = (const half8*)hw;
  float8 acc = {0.f, 0.f, 0.f, 0.f, 0.f, 0.f, 0.f, 0.f};
  if (eslot == 0)  // self loop (pre-scaled row, final *dn below)
    acc = __builtin_convertvector(hw8[(size_t)n * FC + c], float8);

  int j0 = off[n], j1 = off[n + 1];
  int j = j0 + eslot;
  // 4-deep unroll: 4 x 16B gathers in flight per lane
  for (; j + 3 * EPW < j1; j += 4 * EPW) {
    int s0 = csr[j + 0 * EPW];
    int s1 = csr[j + 1 * EPW];
    int s2 = csr[j + 2 * EPW];
    int s3 = csr[j + 3 * EPW];
    half8 v0 = hw8[(size_t)s0 * FC + c];
    half8 v1 = hw8[(size_t)s1 * FC + c];
    half8 v2 = hw8[(size_t)s2 * FC + c];
    half8 v3 = hw8[(size_t)s3 * FC + c];
    acc += __builtin_convertvector(v0, float8);
    acc += __builtin_convertvector(v1, float8);
    acc += __builtin_convertvector(v2, float8);
    acc += __builtin_convertvector(v3, float8);
  }
  for (; j < j1; j += EPW)
    acc += __builtin_convertvector(hw8[(size_t)csr[j] * FC + c], float8);

  // fold edge slots
#pragma unroll
  for (int st = FC; st < 64; st <<= 1) {
#pragma unroll
    for (int i = 0; i < 8; ++i) acc[i] += __shfl_xor(acc[i], st, 64);
  }

  if (eslot == 0) {
    float dn = dis[n];
    float4 b0 = *(const float4*)&bias[c * 8 + 0];
    float4 b1 = *(const float4*)&bias[c * 8 + 4];
    float4 r0 = make_float4(fmaf(acc[0], dn, b0.x), fmaf(acc[1], dn, b0.y),
                            fmaf(acc[2], dn, b0.z), fmaf(acc[3], dn, b0.w));
    float4 r1 = make_float4(fmaf(acc[4], dn, b1.x), fmaf(acc[5], dn, b1.y),
                            fmaf(acc[6], dn, b1.z), fmaf(acc[7], dn, b1.w));
    if (RELU) {
      r0.x = fmaxf(r0.x, 0.f); r0.y = fmaxf(r0.y, 0.f);
      r0.z = fmaxf(r0.z, 0.f); r0.w = fmaxf(r0.w, 0.f);
      r1.x = fmaxf(r1.x, 0.f); r1.y = fmaxf(r1.y, 0.f);
      r1.z = fmaxf(r1.z, 0.f); r1.w = fmaxf(r1.w, 0.f);
    }
    float* op = out + (size_t)n * F + c * 8;
    *(float4*)(op + 0) = r0;
    *(float4*)(op + 4) = r1;
  }
}

extern "C" void kernel_launch(void* const* d_in, const int* in_sizes, int n_in,
                              void* d_out, int out_size, void* d_ws,
                              size_t ws_size, hipStream_t stream) {
  const float* x = (const float*)d_in[0];
  const int* ei = (const int*)d_in[1];
  const float* W1 = (const float*)d_in[2];
  const float* b1 = (const float*)d_in[3];
  const float* W2 = (const float*)d_in[4];
  const float* b2 = (const float*)d_in[5];
  const float* Wc = (const float*)d_in[6];
  const float* bc = (const float*)d_in[7];

  int N = in_sizes[0] / DIN;
  int E = in_sizes[1] / 2;
  int nper = (N + 7) / 8;          // dst-range partition size
  float invn = 1.0f / (float)nper;  // deterministic partition map scale

  char* w = (char*)d_ws;
  size_t off = 0;
  auto alloc = [&](size_t bytes) {
    char* p = w + off;
    off += (bytes + 255) & ~(size_t)255;
    return p;
  };
  int* counts = (int*)alloc((size_t)N * 4);
  int* offsets = (int*)alloc((size_t)(N + 1) * 4);
  int* cursor = (int*)alloc((size_t)N * 4);
  int* csr = (int*)alloc((size_t)E * 4);
  float* dis = (float*)alloc((size_t)N * 4);
  int* blockSums = (int*)alloc((size_t)1024 * 4);
  _Float16* hw1 = (_Float16*)alloc((size_t)N * DIN * 2);  // fp16, dis-scaled
  float* h1 = (float*)alloc((size_t)N * HID * 4);
  _Float16* hw2 = hw1;  // alias: hw1 dead after gather1

  float* out_h2 = (float*)d_out;             // output 0: h2 [N x 64]
  float* out_y = out_h2 + (size_t)N * FOUT;  // output 1: out [N x 64]

  hipMemsetAsync(counts, 0, (size_t)N * 4, stream);

  int egrid = (E + 255) / 256;
  int ngrid = (N + 255) / 256;  // scan chunk count G
  int ggrid = (N + 31) / 32;
  int wgrid = (N + 3) / 4;  // gather: 4 nodes (waves) per block

  hist_kernel<<<egrid * 8, 256, 0, stream>>>(ei, E, counts, invn);
  block_sum_kernel<<<ngrid, 256, 0, stream>>>(counts, N, blockSums);
  scan_blocksums_kernel<<<1, 1024, 0, stream>>>(blockSums, ngrid);
  scan_apply_kernel<<<ngrid, 256, 0, stream>>>(counts, blockSums, N, E,
                                               offsets, cursor, dis);
  fill_kernel<<<egrid * 8, 256, 0, stream>>>(ei, E, cursor, csr, invn);

  // layer 1: hw1 = (x @ W1)*dis (fp16) ; h1 = relu(dn*Agg(hw1) + b1)
  gemm_kernel<DIN, HID, false, true><<<ggrid, 256, 0, stream>>>(
      x, W1, nullptr, dis, hw1, N);
  gather_kernel<HID, true><<<wgrid, 256, 0, stream>>>(hw1, dis, offsets, csr,
                                                      b1, h1, N);

  // layer 2: hw2 = (h1 @ W2)*dis (fp16) ; h2 = dn*Agg(hw2) + b2 -> d_out[0:]
  gemm_kernel<HID, FOUT, false, true><<<ggrid, 256, 0, stream>>>(
      h1, W2, nullptr, dis, hw2, N);
  gather_kernel<FOUT, false><<<wgrid, 256, 0, stream>>>(hw2, dis, offsets, csr,
                                                        b2, out_h2, N);

  // head: out = h2 @ Wc + bc -> d_out[N*64 : 2*N*64]
  gemm_kernel<FOUT, FOUT, true, false><<<ggrid, 256, 0, stream>>>(
      out_h2, Wc, bc, nullptr, out_y, N);
}

// Round 6
// 293.566 us; speedup vs baseline: 1.5038x; 1.0584x over previous
//
#include <hip/hip_runtime.h>

// GCN: h1 = relu(Agg(x@W1) + b1); h2 = Agg(h1@W2) + b2; out = h2@Wc + bc
// Agg = symmetric-normalized adjacency with self-loops (PyG GCNConv).
// CSR build: XCD-partitioned hist/fill (R5: kills 64B/4B write amp + atomic
// line bounce), 3-level scan.
// GEMMs: v_mfma_f32_16x16x32_f16. W transposed to fp16 in LDS once per
// block; B-fragments register-resident for whole K; grid-stride row loop.
// Layouts (guide-verified): A[m=lane&15][k=quad*8+j], B[k=quad*8+j][n=lane&15],
// C col=lane&15, row=quad*4+reg.
// Gather: fp16 rows pre-scaled by dis[src] (gemm epilogue), one node per
// wave, 16B/lane loads, fp32 accumulate.

#define DIN 128
#define HID 128
#define FOUT 64

using half8 = __attribute__((ext_vector_type(8))) _Float16;
using float8 = __attribute__((ext_vector_type(8))) float;
using f32x4 = __attribute__((ext_vector_type(4))) float;

// Deterministic dst->partition map (pure function; locality heuristic only).
__device__ inline int part_of(int d, float invn) {
  int p = (int)((float)d * invn);
  return p > 7 ? 7 : p;
}

// Partitioned histogram: block b = chunk (b>>3) x partition (b&7).
__global__ __launch_bounds__(256) void hist_kernel(
    const int* __restrict__ ei, int E, int* __restrict__ counts, float invn) {
  int part = blockIdx.x & 7;
  int e = (blockIdx.x >> 3) * 256 + threadIdx.x;
  if (e >= E) return;
  int d = ei[E + e];
  if (part_of(d, invn) == part) atomicAdd(&counts[d], 1);
}

// Level 1: per-block sums of 256-count chunks.
__global__ __launch_bounds__(256) void block_sum_kernel(
    const int* __restrict__ counts, int N, int* __restrict__ blockSums) {
  int i = blockIdx.x * 256 + threadIdx.x;
  int v = (i < N) ? counts[i] : 0;
#pragma unroll
  for (int off = 32; off > 0; off >>= 1) v += __shfl_down(v, off, 64);
  __shared__ int ws[4];
  if ((threadIdx.x & 63) == 0) ws[threadIdx.x >> 6] = v;
  __syncthreads();
  if (threadIdx.x == 0)
    blockSums[blockIdx.x] = ws[0] + ws[1] + ws[2] + ws[3];
}

// Level 2: single-block exclusive scan of up to 1024 block sums.
__global__ __launch_bounds__(1024) void scan_blocksums_kernel(
    int* __restrict__ blockSums, int G) {
  __shared__ int s[1024];
  int t = threadIdx.x;
  int v = (t < G) ? blockSums[t] : 0;
  s[t] = v;
  __syncthreads();
  for (int off = 1; off < 1024; off <<= 1) {
    int u = 0;
    if (t >= off) u = s[t - off];
    __syncthreads();
    s[t] += u;
    __syncthreads();
  }
  if (t < G) blockSums[t] = s[t] - v;  // exclusive
}

// Level 3: re-scan chunk, add block offset; fused node_init (dis, cursor).
__global__ __launch_bounds__(256) void scan_apply_kernel(
    const int* __restrict__ counts, const int* __restrict__ blockSums, int N,
    int E, int* __restrict__ offsets, int* __restrict__ cursor,
    float* __restrict__ dis) {
  int t = threadIdx.x;
  int i = blockIdx.x * 256 + t;
  int c = (i < N) ? counts[i] : 0;
  __shared__ int s[256];
  s[t] = c;
  __syncthreads();
  for (int off = 1; off < 256; off <<= 1) {
    int u = 0;
    if (t >= off) u = s[t - off];
    __syncthreads();
    s[t] += u;
    __syncthreads();
  }
  int excl = s[t] - c + blockSums[blockIdx.x];
  if (i < N) {
    offsets[i] = excl;
    cursor[i] = excl;
    dis[i] = rsqrtf((float)c + 1.0f);  // deg includes self-loop
  }
  if (i == N - 1) offsets[N] = E;
}

// Partitioned fill: only XCD (blockIdx&7) writes partition's csr/cursor range.
__global__ __launch_bounds__(256) void fill_kernel(
    const int* __restrict__ ei, int E, int* __restrict__ cursor,
    int* __restrict__ csr, float invn) {
  int part = blockIdx.x & 7;
  int e = (blockIdx.x >> 3) * 256 + threadIdx.x;
  if (e >= E) return;
  int d = ei[E + e];
  if (part_of(d, invn) != part) return;
  int s = ei[e];
  int p = atomicAdd(&cursor[d], 1);
  csr[p] = s;
}

// MFMA GEMM: C[M x NCOL] = A[M x K](fp32) @ W[K x NCOL](fp32), fp16 compute,
// fp32 accumulate. H16: store fp16 * dis[row] (gather operand). Else fp32 +
// bias. Wave owns NCOL/4 cols; B-frags in registers for whole K; grid-stride
// over 32-row chunks.
template <int K, int NCOL, bool H16>
__global__ __launch_bounds__(256) void gemm_mfma_kernel(
    const float* __restrict__ A, const float* __restrict__ W,
    const float* __restrict__ dis, const float* __restrict__ bias,
    void* __restrict__ Cout, int M) {
  constexpr int KP = K + 8;      // half-stride: (K+8)*2 B is 16B-multiple
  constexpr int KS = K / 32;     // k-steps per MFMA chain
  constexpr int NC4 = NCOL / 4;  // cols per wave
  constexpr int CT = NC4 / 16;   // 16-col tiles per wave
  __shared__ _Float16 Wt[NCOL * KP];

  int tid = threadIdx.x;
  // stage + transpose W -> Wt[n][k] fp16 (once per block)
  for (int i = tid; i < K * NCOL / 4; i += 256) {
    int k = i / (NCOL / 4);
    int n0 = (i % (NCOL / 4)) * 4;
    float4 w = *(const float4*)&W[(size_t)k * NCOL + n0];
    Wt[(n0 + 0) * KP + k] = (_Float16)w.x;
    Wt[(n0 + 1) * KP + k] = (_Float16)w.y;
    Wt[(n0 + 2) * KP + k] = (_Float16)w.z;
    Wt[(n0 + 3) * KP + k] = (_Float16)w.w;
  }
  __syncthreads();

  int wave = tid >> 6, lane = tid & 63;
  int m = lane & 15, quad = lane >> 4;
  int cw = wave * NC4;

  // B fragments: B[k=quad*8+j][n=cw+ct*16+m], register-resident for whole K
  half8 b[CT][KS];
#pragma unroll
  for (int ct = 0; ct < CT; ++ct)
#pragma unroll
    for (int s = 0; s < KS; ++s)
      b[ct][s] =
          *(half8*)&Wt[(size_t)(cw + ct * 16 + m) * KP + s * 32 + quad * 8];

  float bval[CT];  // bias per (ct): col fixed per lane (chunk-invariant)
#pragma unroll
  for (int ct = 0; ct < CT; ++ct)
    bval[ct] = H16 ? 0.f : bias[cw + ct * 16 + m];

  int nch = (M + 31) >> 5;
  for (int ch = blockIdx.x; ch < nch; ch += gridDim.x) {
    int r0 = ch << 5;
    f32x4 acc[2][CT];
#pragma unroll
    for (int rt = 0; rt < 2; ++rt)
#pragma unroll
      for (int ct = 0; ct < CT; ++ct) acc[rt][ct] = (f32x4){0.f, 0.f, 0.f, 0.f};

#pragma unroll
    for (int rt = 0; rt < 2; ++rt) {
      int row = r0 + rt * 16 + m;
      bool ok = row < M;
      const float* ap = A + (size_t)row * K + quad * 8;
#pragma unroll
      for (int s = 0; s < KS; ++s) {
        float4 a0 = make_float4(0.f, 0.f, 0.f, 0.f), a1 = a0;
        if (ok) {
          a0 = *(const float4*)(ap + s * 32);
          a1 = *(const float4*)(ap + s * 32 + 4);
        }
        half8 af;
        af[0] = (_Float16)a0.x; af[1] = (_Float16)a0.y;
        af[2] = (_Float16)a0.z; af[3] = (_Float16)a0.w;
        af[4] = (_Float16)a1.x; af[5] = (_Float16)a1.y;
        af[6] = (_Float16)a1.z; af[7] = (_Float16)a1.w;
#pragma unroll
        for (int ct = 0; ct < CT; ++ct)
          acc[rt][ct] = __builtin_amdgcn_mfma_f32_16x16x32_f16(
              af, b[ct][s], acc[rt][ct], 0, 0, 0);
      }
    }

    // epilogue: C col = cw+ct*16+m, row = r0+rt*16+quad*4+i
#pragma unroll
    for (int rt = 0; rt < 2; ++rt) {
#pragma unroll
      for (int i = 0; i < 4; ++i) {
        int row = r0 + rt * 16 + quad * 4 + i;
        if (row >= M) continue;
        if (H16) {
          float d = dis[row];
#pragma unroll
          for (int ct = 0; ct < CT; ++ct)
            ((_Float16*)Cout)[(size_t)row * NCOL + cw + ct * 16 + m] =
                (_Float16)(acc[rt][ct][i] * d);
        } else {
#pragma unroll
          for (int ct = 0; ct < CT; ++ct)
            ((float*)Cout)[(size_t)row * NCOL + cw + ct * 16 + m] =
                acc[rt][ct][i] + bval[ct];
        }
      }
    }
  }
}

// Gather segment-sum over pre-scaled fp16 rows, one node per 64-lane wave.
// Lanes = EPW edge-slots x FC half8 feature chunks (16B/lane loads).
// out[n][:] = dis[n] * (sum_{s in N(n)} hws[s][:] + hws[n][:]) + bias
// where hws[r] = (h@W)[r] * dis[r] (done in gemm epilogue). fp32 accumulate.
template <int F, bool RELU>
__global__ __launch_bounds__(256) void gather_kernel(
    const _Float16* __restrict__ hw, const float* __restrict__ dis,
    const int* __restrict__ off, const int* __restrict__ csr,
    const float* __restrict__ bias, float* __restrict__ out, int N) {
  constexpr int FC = F / 8;     // half8 chunks per row (16 or 8)
  constexpr int EPW = 64 / FC;  // edge slots per wave (4 or 8)
  int wave = threadIdx.x >> 6;
  int lane = threadIdx.x & 63;
  int eslot = lane / FC;
  int c = lane % FC;
  int n = blockIdx.x * 4 + wave;
  if (n >= N) return;

  const half8* hw8 = (const half8*)hw;
  float8 acc = {0.f, 0.f, 0.f, 0.f, 0.f, 0.f, 0.f, 0.f};
  if (eslot == 0)  // self loop (pre-scaled row, final *dn below)
    acc = __builtin_convertvector(hw8[(size_t)n * FC + c], float8);

  int j0 = off[n], j1 = off[n + 1];
  int j = j0 + eslot;
  // 4-deep unroll: 4 x 16B gathers in flight per lane
  for (; j + 3 * EPW < j1; j += 4 * EPW) {
    int s0 = csr[j + 0 * EPW];
    int s1 = csr[j + 1 * EPW];
    int s2 = csr[j + 2 * EPW];
    int s3 = csr[j + 3 * EPW];
    half8 v0 = hw8[(size_t)s0 * FC + c];
    half8 v1 = hw8[(size_t)s1 * FC + c];
    half8 v2 = hw8[(size_t)s2 * FC + c];
    half8 v3 = hw8[(size_t)s3 * FC + c];
    acc += __builtin_convertvector(v0, float8);
    acc += __builtin_convertvector(v1, float8);
    acc += __builtin_convertvector(v2, float8);
    acc += __builtin_convertvector(v3, float8);
  }
  for (; j < j1; j += EPW)
    acc += __builtin_convertvector(hw8[(size_t)csr[j] * FC + c], float8);

  // fold edge slots
#pragma unroll
  for (int st = FC; st < 64; st <<= 1) {
#pragma unroll
    for (int i = 0; i < 8; ++i) acc[i] += __shfl_xor(acc[i], st, 64);
  }

  if (eslot == 0) {
    float dn = dis[n];
    float4 b0 = *(const float4*)&bias[c * 8 + 0];
    float4 b1 = *(const float4*)&bias[c * 8 + 4];
    float4 r0 = make_float4(fmaf(acc[0], dn, b0.x), fmaf(acc[1], dn, b0.y),
                            fmaf(acc[2], dn, b0.z), fmaf(acc[3], dn, b0.w));
    float4 r1 = make_float4(fmaf(acc[4], dn, b1.x), fmaf(acc[5], dn, b1.y),
                            fmaf(acc[6], dn, b1.z), fmaf(acc[7], dn, b1.w));
    if (RELU) {
      r0.x = fmaxf(r0.x, 0.f); r0.y = fmaxf(r0.y, 0.f);
      r0.z = fmaxf(r0.z, 0.f); r0.w = fmaxf(r0.w, 0.f);
      r1.x = fmaxf(r1.x, 0.f); r1.y = fmaxf(r1.y, 0.f);
      r1.z = fmaxf(r1.z, 0.f); r1.w = fmaxf(r1.w, 0.f);
    }
    float* op = out + (size_t)n * F + c * 8;
    *(float4*)(op + 0) = r0;
    *(float4*)(op + 4) = r1;
  }
}

extern "C" void kernel_launch(void* const* d_in, const int* in_sizes, int n_in,
                              void* d_out, int out_size, void* d_ws,
                              size_t ws_size, hipStream_t stream) {
  const float* x = (const float*)d_in[0];
  const int* ei = (const int*)d_in[1];
  const float* W1 = (const float*)d_in[2];
  const float* b1 = (const float*)d_in[3];
  const float* W2 = (const float*)d_in[4];
  const float* b2 = (const float*)d_in[5];
  const float* Wc = (const float*)d_in[6];
  const float* bc = (const float*)d_in[7];

  int N = in_sizes[0] / DIN;
  int E = in_sizes[1] / 2;
  int nper = (N + 7) / 8;           // dst-range partition size
  float invn = 1.0f / (float)nper;  // deterministic partition map scale

  char* w = (char*)d_ws;
  size_t off = 0;
  auto alloc = [&](size_t bytes) {
    char* p = w + off;
    off += (bytes + 255) & ~(size_t)255;
    return p;
  };
  int* counts = (int*)alloc((size_t)N * 4);
  int* offsets = (int*)alloc((size_t)(N + 1) * 4);
  int* cursor = (int*)alloc((size_t)N * 4);
  int* csr = (int*)alloc((size_t)E * 4);
  float* dis = (float*)alloc((size_t)N * 4);
  int* blockSums = (int*)alloc((size_t)1024 * 4);
  _Float16* hw1 = (_Float16*)alloc((size_t)N * DIN * 2);  // fp16, dis-scaled
  float* h1 = (float*)alloc((size_t)N * HID * 4);
  _Float16* hw2 = hw1;  // alias: hw1 dead after gather1

  float* out_h2 = (float*)d_out;             // output 0: h2 [N x 64]
  float* out_y = out_h2 + (size_t)N * FOUT;  // output 1: out [N x 64]

  hipMemsetAsync(counts, 0, (size_t)N * 4, stream);

  int egrid = (E + 255) / 256;
  int ngrid = (N + 255) / 256;  // scan chunk count G
  int wgrid = (N + 3) / 4;      // gather: 4 nodes (waves) per block

  hist_kernel<<<egrid * 8, 256, 0, stream>>>(ei, E, counts, invn);
  block_sum_kernel<<<ngrid, 256, 0, stream>>>(counts, N, blockSums);
  scan_blocksums_kernel<<<1, 1024, 0, stream>>>(blockSums, ngrid);
  scan_apply_kernel<<<ngrid, 256, 0, stream>>>(counts, blockSums, N, E,
                                               offsets, cursor, dis);
  fill_kernel<<<egrid * 8, 256, 0, stream>>>(ei, E, cursor, csr, invn);

  // layer 1: hw1 = (x @ W1)*dis (fp16) ; h1 = relu(dn*Agg(hw1) + b1)
  gemm_mfma_kernel<DIN, HID, true><<<512, 256, 0, stream>>>(
      x, W1, dis, nullptr, hw1, N);
  gather_kernel<HID, true><<<wgrid, 256, 0, stream>>>(hw1, dis, offsets, csr,
                                                      b1, h1, N);

  // layer 2: hw2 = (h1 @ W2)*dis (fp16) ; h2 = dn*Agg(hw2) + b2 -> d_out[0:]
  gemm_mfma_kernel<HID, FOUT, true><<<512, 256, 0, stream>>>(
      h1, W2, dis, nullptr, hw2, N);
  gather_kernel<FOUT, false><<<wgrid, 256, 0, stream>>>(hw2, dis, offsets, csr,
                                                        b2, out_h2, N);

  // head: out = h2 @ Wc + bc -> d_out[N*64 : 2*N*64]
  gemm_mfma_kernel<FOUT, FOUT, false><<<512, 256, 0, stream>>>(
      out_h2, Wc, nullptr, bc, out_y, N);
}

// Round 7
// 290.626 us; speedup vs baseline: 1.5190x; 1.0101x over previous
//
#include <hip/hip_runtime.h>

// GCN: h1 = relu(Agg(x@W1) + b1); h2 = Agg(h1@W2) + b2; out = h2@Wc + bc
// Agg = symmetric-normalized adjacency with self-loops (PyG GCNConv).
// CSR build: XCD-partitioned hist/fill (R5), 3-level scan.
// GEMMs: v_mfma_f32_16x16x32_f16, W transposed to fp16 LDS, B-frags
// register-resident, grid-stride rows. h1 kept fp16 (identical rounding to
// the old fp32->fp16 convert in gemm2's A path; halves h1 traffic).
// Head GEMM fused into gather<64>: Wc staged in LDS, per-node h2 row
// round-trips a per-wave LDS buffer (wave-local, no barrier), 64 lanes
// each produce one output column. Kills gemm3 launch + 12.8MB h2 re-read.
// Gather: fp16 rows pre-scaled by dis[src], one node per wave, 16B/lane.

#define DIN 128
#define HID 128
#define FOUT 64

using half8 = __attribute__((ext_vector_type(8))) _Float16;
using float8 = __attribute__((ext_vector_type(8))) float;
using f32x4 = __attribute__((ext_vector_type(4))) float;

// Deterministic dst->partition map (pure function; locality heuristic only).
__device__ inline int part_of(int d, float invn) {
  int p = (int)((float)d * invn);
  return p > 7 ? 7 : p;
}

// Partitioned histogram: block b = chunk (b>>3) x partition (b&7).
__global__ __launch_bounds__(256) void hist_kernel(
    const int* __restrict__ ei, int E, int* __restrict__ counts, float invn) {
  int part = blockIdx.x & 7;
  int e = (blockIdx.x >> 3) * 256 + threadIdx.x;
  if (e >= E) return;
  int d = ei[E + e];
  if (part_of(d, invn) == part) atomicAdd(&counts[d], 1);
}

// Level 1: per-block sums of 256-count chunks.
__global__ __launch_bounds__(256) void block_sum_kernel(
    const int* __restrict__ counts, int N, int* __restrict__ blockSums) {
  int i = blockIdx.x * 256 + threadIdx.x;
  int v = (i < N) ? counts[i] : 0;
#pragma unroll
  for (int off = 32; off > 0; off >>= 1) v += __shfl_down(v, off, 64);
  __shared__ int ws[4];
  if ((threadIdx.x & 63) == 0) ws[threadIdx.x >> 6] = v;
  __syncthreads();
  if (threadIdx.x == 0)
    blockSums[blockIdx.x] = ws[0] + ws[1] + ws[2] + ws[3];
}

// Level 2: single-block exclusive scan of up to 1024 block sums.
__global__ __launch_bounds__(1024) void scan_blocksums_kernel(
    int* __restrict__ blockSums, int G) {
  __shared__ int s[1024];
  int t = threadIdx.x;
  int v = (t < G) ? blockSums[t] : 0;
  s[t] = v;
  __syncthreads();
  for (int off = 1; off < 1024; off <<= 1) {
    int u = 0;
    if (t >= off) u = s[t - off];
    __syncthreads();
    s[t] += u;
    __syncthreads();
  }
  if (t < G) blockSums[t] = s[t] - v;  // exclusive
}

// Level 3: re-scan chunk, add block offset; fused node_init (dis, cursor).
__global__ __launch_bounds__(256) void scan_apply_kernel(
    const int* __restrict__ counts, const int* __restrict__ blockSums, int N,
    int E, int* __restrict__ offsets, int* __restrict__ cursor,
    float* __restrict__ dis) {
  int t = threadIdx.x;
  int i = blockIdx.x * 256 + t;
  int c = (i < N) ? counts[i] : 0;
  __shared__ int s[256];
  s[t] = c;
  __syncthreads();
  for (int off = 1; off < 256; off <<= 1) {
    int u = 0;
    if (t >= off) u = s[t - off];
    __syncthreads();
    s[t] += u;
    __syncthreads();
  }
  int excl = s[t] - c + blockSums[blockIdx.x];
  if (i < N) {
    offsets[i] = excl;
    cursor[i] = excl;
    dis[i] = rsqrtf((float)c + 1.0f);  // deg includes self-loop
  }
  if (i == N - 1) offsets[N] = E;
}

// Partitioned fill: only XCD (blockIdx&7) writes partition's csr/cursor range.
__global__ __launch_bounds__(256) void fill_kernel(
    const int* __restrict__ ei, int E, int* __restrict__ cursor,
    int* __restrict__ csr, float invn) {
  int part = blockIdx.x & 7;
  int e = (blockIdx.x >> 3) * 256 + threadIdx.x;
  if (e >= E) return;
  int d = ei[E + e];
  if (part_of(d, invn) != part) return;
  int s = ei[e];
  int p = atomicAdd(&cursor[d], 1);
  csr[p] = s;
}

// MFMA GEMM: C[M x NCOL] = A[M x K] @ W[K x NCOL](fp32), fp16 compute, fp32
// accumulate. AH: A is fp16. Stores fp16 * dis[row] (gather operand).
// Wave owns NCOL/4 cols; B-frags in registers for whole K; grid-stride rows.
template <int K, int NCOL, bool AH>
__global__ __launch_bounds__(256) void gemm_mfma_kernel(
    const void* __restrict__ A, const float* __restrict__ W,
    const float* __restrict__ dis, _Float16* __restrict__ Cout, int M) {
  constexpr int KP = K + 8;      // half-stride: (K+8)*2 B is 16B-multiple
  constexpr int KS = K / 32;     // k-steps per MFMA chain
  constexpr int NC4 = NCOL / 4;  // cols per wave
  constexpr int CT = NC4 / 16;   // 16-col tiles per wave
  __shared__ _Float16 Wt[NCOL * KP];

  int tid = threadIdx.x;
  // stage + transpose W -> Wt[n][k] fp16 (once per block)
  for (int i = tid; i < K * NCOL / 4; i += 256) {
    int k = i / (NCOL / 4);
    int n0 = (i % (NCOL / 4)) * 4;
    float4 w = *(const float4*)&W[(size_t)k * NCOL + n0];
    Wt[(n0 + 0) * KP + k] = (_Float16)w.x;
    Wt[(n0 + 1) * KP + k] = (_Float16)w.y;
    Wt[(n0 + 2) * KP + k] = (_Float16)w.z;
    Wt[(n0 + 3) * KP + k] = (_Float16)w.w;
  }
  __syncthreads();

  int wave = tid >> 6, lane = tid & 63;
  int m = lane & 15, quad = lane >> 4;
  int cw = wave * NC4;

  // B fragments: B[k=quad*8+j][n=cw+ct*16+m], register-resident for whole K
  half8 b[CT][KS];
#pragma unroll
  for (int ct = 0; ct < CT; ++ct)
#pragma unroll
    for (int s = 0; s < KS; ++s)
      b[ct][s] =
          *(half8*)&Wt[(size_t)(cw + ct * 16 + m) * KP + s * 32 + quad * 8];

  int nch = (M + 31) >> 5;
  for (int ch = blockIdx.x; ch < nch; ch += gridDim.x) {
    int r0 = ch << 5;
    f32x4 acc[2][CT];
#pragma unroll
    for (int rt = 0; rt < 2; ++rt)
#pragma unroll
      for (int ct = 0; ct < CT; ++ct) acc[rt][ct] = (f32x4){0.f, 0.f, 0.f, 0.f};

#pragma unroll
    for (int rt = 0; rt < 2; ++rt) {
      int row = r0 + rt * 16 + m;
      bool ok = row < M;
#pragma unroll
      for (int s = 0; s < KS; ++s) {
        half8 af = (half8)(_Float16)0;
        if (ok) {
          if (AH) {
            af = *(const half8*)((const _Float16*)A + (size_t)row * K +
                                 s * 32 + quad * 8);
          } else {
            const float* ap = (const float*)A + (size_t)row * K + quad * 8;
            float4 a0 = *(const float4*)(ap + s * 32);
            float4 a1 = *(const float4*)(ap + s * 32 + 4);
            af[0] = (_Float16)a0.x; af[1] = (_Float16)a0.y;
            af[2] = (_Float16)a0.z; af[3] = (_Float16)a0.w;
            af[4] = (_Float16)a1.x; af[5] = (_Float16)a1.y;
            af[6] = (_Float16)a1.z; af[7] = (_Float16)a1.w;
          }
        }
#pragma unroll
        for (int ct = 0; ct < CT; ++ct)
          acc[rt][ct] = __builtin_amdgcn_mfma_f32_16x16x32_f16(
              af, b[ct][s], acc[rt][ct], 0, 0, 0);
      }
    }

    // epilogue: C col = cw+ct*16+m, row = r0+rt*16+quad*4+i; store fp16*dis
#pragma unroll
    for (int rt = 0; rt < 2; ++rt) {
#pragma unroll
      for (int i = 0; i < 4; ++i) {
        int row = r0 + rt * 16 + quad * 4 + i;
        if (row >= M) continue;
        float d = dis[row];
#pragma unroll
        for (int ct = 0; ct < CT; ++ct)
          Cout[(size_t)row * NCOL + cw + ct * 16 + m] =
              (_Float16)(acc[rt][ct][i] * d);
      }
    }
  }
}

// Gather segment-sum over pre-scaled fp16 rows, one node per 64-lane wave,
// fp16 output + relu (layer 1). Lanes = EPW edge-slots x FC half8 chunks.
// h1[n][:] = relu(dis[n] * (sum_{s in N(n)} hws[s] + hws[n]) + bias), fp16.
template <int F>
__global__ __launch_bounds__(256) void gather_relu_kernel(
    const _Float16* __restrict__ hw, const float* __restrict__ dis,
    const int* __restrict__ off, const int* __restrict__ csr,
    const float* __restrict__ bias, _Float16* __restrict__ out, int N) {
  constexpr int FC = F / 8;
  constexpr int EPW = 64 / FC;
  int wave = threadIdx.x >> 6;
  int lane = threadIdx.x & 63;
  int eslot = lane / FC;
  int c = lane % FC;
  int n = blockIdx.x * 4 + wave;
  if (n >= N) return;

  const half8* hw8 = (const half8*)hw;
  float8 acc = {0.f, 0.f, 0.f, 0.f, 0.f, 0.f, 0.f, 0.f};
  if (eslot == 0)  // self loop
    acc = __builtin_convertvector(hw8[(size_t)n * FC + c], float8);

  int j0 = off[n], j1 = off[n + 1];
  int j = j0 + eslot;
  for (; j + 3 * EPW < j1; j += 4 * EPW) {
    int s0 = csr[j + 0 * EPW];
    int s1 = csr[j + 1 * EPW];
    int s2 = csr[j + 2 * EPW];
    int s3 = csr[j + 3 * EPW];
    half8 v0 = hw8[(size_t)s0 * FC + c];
    half8 v1 = hw8[(size_t)s1 * FC + c];
    half8 v2 = hw8[(size_t)s2 * FC + c];
    half8 v3 = hw8[(size_t)s3 * FC + c];
    acc += __builtin_convertvector(v0, float8);
    acc += __builtin_convertvector(v1, float8);
    acc += __builtin_convertvector(v2, float8);
    acc += __builtin_convertvector(v3, float8);
  }
  for (; j < j1; j += EPW)
    acc += __builtin_convertvector(hw8[(size_t)csr[j] * FC + c], float8);

#pragma unroll
  for (int st = FC; st < 64; st <<= 1) {
#pragma unroll
    for (int i = 0; i < 8; ++i) acc[i] += __shfl_xor(acc[i], st, 64);
  }

  if (eslot == 0) {
    float dn = dis[n];
    half8 h;
#pragma unroll
    for (int i = 0; i < 8; ++i)
      h[i] = (_Float16)fmaxf(fmaf(acc[i], dn, bias[c * 8 + i]), 0.f);
    *(half8*)(out + (size_t)n * F + c * 8) = h;
  }
}

// Layer-2 gather + fused head GEMM. F=64. Grid-stride over nodes.
// h2[n] = dis[n]*(sum hws2[s] + hws2[n]) + b2  -> out_h2 (fp32, output 0)
// y[n]  = h2[n] @ Wc + bc                      -> out_y  (fp32, output 1)
// Wc staged in LDS (fp32, 16KB); per-node h2 row round-trips per-wave LDS
// buffer (wave-local ordering, no barrier); lane j computes y column j.
__global__ __launch_bounds__(256) void gather_head_kernel(
    const _Float16* __restrict__ hw, const float* __restrict__ dis,
    const int* __restrict__ off, const int* __restrict__ csr,
    const float* __restrict__ b2, const float* __restrict__ Wc,
    const float* __restrict__ bc, float* __restrict__ out_h2,
    float* __restrict__ out_y, int N) {
  constexpr int F = 64;
  constexpr int FC = F / 8;     // 8 half8 chunks per row
  constexpr int EPW = 64 / FC;  // 8 edge slots per wave
  __shared__ float WcS[64 * 64];   // WcS[k*64+n] (16KB)
  __shared__ float h2buf[4][64];   // per-wave h2 row

  int tid = threadIdx.x;
  for (int i = tid; i < 64 * 64; i += 256) WcS[i] = Wc[i];
  __syncthreads();

  int wave = tid >> 6;
  int lane = tid & 63;
  int eslot = lane / FC;
  int c = lane % FC;
  float bcv = bc[lane];
  const half8* hw8 = (const half8*)hw;

  for (int n = blockIdx.x * 4 + wave; n < N; n += gridDim.x * 4) {
    float8 acc = {0.f, 0.f, 0.f, 0.f, 0.f, 0.f, 0.f, 0.f};
    if (eslot == 0)  // self loop
      acc = __builtin_convertvector(hw8[(size_t)n * FC + c], float8);

    int j0 = off[n], j1 = off[n + 1];
    int j = j0 + eslot;
    for (; j + 3 * EPW < j1; j += 4 * EPW) {
      int s0 = csr[j + 0 * EPW];
      int s1 = csr[j + 1 * EPW];
      int s2 = csr[j + 2 * EPW];
      int s3 = csr[j + 3 * EPW];
      half8 v0 = hw8[(size_t)s0 * FC + c];
      half8 v1 = hw8[(size_t)s1 * FC + c];
      half8 v2 = hw8[(size_t)s2 * FC + c];
      half8 v3 = hw8[(size_t)s3 * FC + c];
      acc += __builtin_convertvector(v0, float8);
      acc += __builtin_convertvector(v1, float8);
      acc += __builtin_convertvector(v2, float8);
      acc += __builtin_convertvector(v3, float8);
    }
    for (; j < j1; j += EPW)
      acc += __builtin_convertvector(hw8[(size_t)csr[j] * FC + c], float8);

#pragma unroll
    for (int st = FC; st < 64; st <<= 1) {
#pragma unroll
      for (int i = 0; i < 8; ++i) acc[i] += __shfl_xor(acc[i], st, 64);
    }

    if (eslot == 0) {
      float dn = dis[n];
      float4 b0 = *(const float4*)&b2[c * 8 + 0];
      float4 b1 = *(const float4*)&b2[c * 8 + 4];
      float4 r0 = make_float4(fmaf(acc[0], dn, b0.x), fmaf(acc[1], dn, b0.y),
                              fmaf(acc[2], dn, b0.z), fmaf(acc[3], dn, b0.w));
      float4 r1 = make_float4(fmaf(acc[4], dn, b1.x), fmaf(acc[5], dn, b1.y),
                              fmaf(acc[6], dn, b1.z), fmaf(acc[7], dn, b1.w));
      float* op = out_h2 + (size_t)n * F + c * 8;
      *(float4*)(op + 0) = r0;
      *(float4*)(op + 4) = r1;
      *(float4*)&h2buf[wave][c * 8 + 0] = r0;
      *(float4*)&h2buf[wave][c * 8 + 4] = r1;
    }

    // head matvec: y[n][lane] = sum_k h2[k]*Wc[k][lane] + bc[lane].
    // h2buf read is wave-local after same-wave write (LDS ops in-order).
    float sum = bcv;
#pragma unroll
    for (int k4 = 0; k4 < 16; ++k4) {
      float4 hh = *(const float4*)&h2buf[wave][k4 * 4];
      sum = fmaf(hh.x, WcS[(k4 * 4 + 0) * 64 + lane], sum);
      sum = fmaf(hh.y, WcS[(k4 * 4 + 1) * 64 + lane], sum);
      sum = fmaf(hh.z, WcS[(k4 * 4 + 2) * 64 + lane], sum);
      sum = fmaf(hh.w, WcS[(k4 * 4 + 3) * 64 + lane], sum);
    }
    out_y[(size_t)n * F + lane] = sum;
  }
}

extern "C" void kernel_launch(void* const* d_in, const int* in_sizes, int n_in,
                              void* d_out, int out_size, void* d_ws,
                              size_t ws_size, hipStream_t stream) {
  const float* x = (const float*)d_in[0];
  const int* ei = (const int*)d_in[1];
  const float* W1 = (const float*)d_in[2];
  const float* b1 = (const float*)d_in[3];
  const float* W2 = (const float*)d_in[4];
  const float* b2 = (const float*)d_in[5];
  const float* Wc = (const float*)d_in[6];
  const float* bc = (const float*)d_in[7];

  int N = in_sizes[0] / DIN;
  int E = in_sizes[1] / 2;
  int nper = (N + 7) / 8;           // dst-range partition size
  float invn = 1.0f / (float)nper;  // deterministic partition map scale

  char* w = (char*)d_ws;
  size_t off = 0;
  auto alloc = [&](size_t bytes) {
    char* p = w + off;
    off += (bytes + 255) & ~(size_t)255;
    return p;
  };
  int* counts = (int*)alloc((size_t)N * 4);
  int* offsets = (int*)alloc((size_t)(N + 1) * 4);
  int* cursor = (int*)alloc((size_t)N * 4);
  int* csr = (int*)alloc((size_t)E * 4);
  float* dis = (float*)alloc((size_t)N * 4);
  int* blockSums = (int*)alloc((size_t)1024 * 4);
  _Float16* hw1 = (_Float16*)alloc((size_t)N * DIN * 2);  // fp16, dis-scaled
  _Float16* h1 = (_Float16*)alloc((size_t)N * HID * 2);   // fp16
  _Float16* hw2 = hw1;  // alias: hw1 dead after gather1

  float* out_h2 = (float*)d_out;             // output 0: h2 [N x 64]
  float* out_y = out_h2 + (size_t)N * FOUT;  // output 1: out [N x 64]

  hipMemsetAsync(counts, 0, (size_t)N * 4, stream);

  int egrid = (E + 255) / 256;
  int ngrid = (N + 255) / 256;  // scan chunk count G
  int wgrid = (N + 3) / 4;      // gather1: 4 nodes (waves) per block

  hist_kernel<<<egrid * 8, 256, 0, stream>>>(ei, E, counts, invn);
  block_sum_kernel<<<ngrid, 256, 0, stream>>>(counts, N, blockSums);
  scan_blocksums_kernel<<<1, 1024, 0, stream>>>(blockSums, ngrid);
  scan_apply_kernel<<<ngrid, 256, 0, stream>>>(counts, blockSums, N, E,
                                               offsets, cursor, dis);
  fill_kernel<<<egrid * 8, 256, 0, stream>>>(ei, E, cursor, csr, invn);

  // layer 1: hw1 = (x @ W1)*dis (fp16) ; h1 = relu(dn*Agg(hw1) + b1) (fp16)
  gemm_mfma_kernel<DIN, HID, false><<<512, 256, 0, stream>>>(
      x, W1, dis, hw1, N);
  gather_relu_kernel<HID><<<wgrid, 256, 0, stream>>>(hw1, dis, offsets, csr,
                                                     b1, h1, N);

  // layer 2: hw2 = (h1 @ W2)*dis (fp16)
  gemm_mfma_kernel<HID, FOUT, true><<<512, 256, 0, stream>>>(
      h1, W2, dis, hw2, N);

  // fused: h2 = dn*Agg(hw2) + b2 -> out_h2 ; out_y = h2 @ Wc + bc
  gather_head_kernel<<<1024, 256, 0, stream>>>(hw2, dis, offsets, csr, b2, Wc,
                                               bc, out_h2, out_y, N);
}

// Round 8
// 286.527 us; speedup vs baseline: 1.5407x; 1.0143x over previous
//
#include <hip/hip_runtime.h>

// GCN: h1 = relu(Agg(x@W1) + b1); h2 = Agg(h1@W2) + b2; out = h2@Wc + bc
// Agg = symmetric-normalized adjacency with self-loops (PyG GCNConv).
// CSR build: XCD-partitioned hist/fill (R5), 3-level scan.
// GEMMs: v_mfma_f32_16x16x32_f16, W transposed to fp16 LDS, B-frags
// register-resident, grid-stride rows. h1 fp16 end-to-end.
// R8: de-fused the head (R7's per-node LDS matvec burned ~30us of scalar
// ds_read_b32; streaming h2 re-read is ~free) — head is an MFMA GEMM
// reading fp32 h2 straight from d_out.
// Gather: fp16 rows pre-scaled by dis[src], one node per wave, 16B/lane.

#define DIN 128
#define HID 128
#define FOUT 64

using half8 = __attribute__((ext_vector_type(8))) _Float16;
using float8 = __attribute__((ext_vector_type(8))) float;
using f32x4 = __attribute__((ext_vector_type(4))) float;

// Deterministic dst->partition map (pure function; locality heuristic only).
__device__ inline int part_of(int d, float invn) {
  int p = (int)((float)d * invn);
  return p > 7 ? 7 : p;
}

// Partitioned histogram: block b = chunk (b>>3) x partition (b&7).
__global__ __launch_bounds__(256) void hist_kernel(
    const int* __restrict__ ei, int E, int* __restrict__ counts, float invn) {
  int part = blockIdx.x & 7;
  int e = (blockIdx.x >> 3) * 256 + threadIdx.x;
  if (e >= E) return;
  int d = ei[E + e];
  if (part_of(d, invn) == part) atomicAdd(&counts[d], 1);
}

// Level 1: per-block sums of 256-count chunks.
__global__ __launch_bounds__(256) void block_sum_kernel(
    const int* __restrict__ counts, int N, int* __restrict__ blockSums) {
  int i = blockIdx.x * 256 + threadIdx.x;
  int v = (i < N) ? counts[i] : 0;
#pragma unroll
  for (int off = 32; off > 0; off >>= 1) v += __shfl_down(v, off, 64);
  __shared__ int ws[4];
  if ((threadIdx.x & 63) == 0) ws[threadIdx.x >> 6] = v;
  __syncthreads();
  if (threadIdx.x == 0)
    blockSums[blockIdx.x] = ws[0] + ws[1] + ws[2] + ws[3];
}

// Level 2: single-block exclusive scan of up to 1024 block sums.
__global__ __launch_bounds__(1024) void scan_blocksums_kernel(
    int* __restrict__ blockSums, int G) {
  __shared__ int s[1024];
  int t = threadIdx.x;
  int v = (t < G) ? blockSums[t] : 0;
  s[t] = v;
  __syncthreads();
  for (int off = 1; off < 1024; off <<= 1) {
    int u = 0;
    if (t >= off) u = s[t - off];
    __syncthreads();
    s[t] += u;
    __syncthreads();
  }
  if (t < G) blockSums[t] = s[t] - v;  // exclusive
}

// Level 3: re-scan chunk, add block offset; fused node_init (dis, cursor).
__global__ __launch_bounds__(256) void scan_apply_kernel(
    const int* __restrict__ counts, const int* __restrict__ blockSums, int N,
    int E, int* __restrict__ offsets, int* __restrict__ cursor,
    float* __restrict__ dis) {
  int t = threadIdx.x;
  int i = blockIdx.x * 256 + t;
  int c = (i < N) ? counts[i] : 0;
  __shared__ int s[256];
  s[t] = c;
  __syncthreads();
  for (int off = 1; off < 256; off <<= 1) {
    int u = 0;
    if (t >= off) u = s[t - off];
    __syncthreads();
    s[t] += u;
    __syncthreads();
  }
  int excl = s[t] - c + blockSums[blockIdx.x];
  if (i < N) {
    offsets[i] = excl;
    cursor[i] = excl;
    dis[i] = rsqrtf((float)c + 1.0f);  // deg includes self-loop
  }
  if (i == N - 1) offsets[N] = E;
}

// Partitioned fill: only XCD (blockIdx&7) writes partition's csr/cursor range.
__global__ __launch_bounds__(256) void fill_kernel(
    const int* __restrict__ ei, int E, int* __restrict__ cursor,
    int* __restrict__ csr, float invn) {
  int part = blockIdx.x & 7;
  int e = (blockIdx.x >> 3) * 256 + threadIdx.x;
  if (e >= E) return;
  int d = ei[E + e];
  if (part_of(d, invn) != part) return;
  int s = ei[e];
  int p = atomicAdd(&cursor[d], 1);
  csr[p] = s;
}

// MFMA GEMM: C[M x NCOL] = A[M x K] @ W[K x NCOL](fp32), fp16 compute, fp32
// accumulate. AH: A is fp16 (else fp32, converted in-register).
// H16: store fp16 * dis[row] (gather operand); else fp32 + bias.
// Wave owns NCOL/4 cols; B-frags in registers for whole K; grid-stride rows.
template <int K, int NCOL, bool AH, bool H16>
__global__ __launch_bounds__(256) void gemm_mfma_kernel(
    const void* __restrict__ A, const float* __restrict__ W,
    const float* __restrict__ dis, const float* __restrict__ bias,
    void* __restrict__ Cout, int M) {
  constexpr int KP = K + 8;      // half-stride: (K+8)*2 B is 16B-multiple
  constexpr int KS = K / 32;     // k-steps per MFMA chain
  constexpr int NC4 = NCOL / 4;  // cols per wave
  constexpr int CT = NC4 / 16;   // 16-col tiles per wave
  __shared__ _Float16 Wt[NCOL * KP];

  int tid = threadIdx.x;
  // stage + transpose W -> Wt[n][k] fp16 (once per block)
  for (int i = tid; i < K * NCOL / 4; i += 256) {
    int k = i / (NCOL / 4);
    int n0 = (i % (NCOL / 4)) * 4;
    float4 w = *(const float4*)&W[(size_t)k * NCOL + n0];
    Wt[(n0 + 0) * KP + k] = (_Float16)w.x;
    Wt[(n0 + 1) * KP + k] = (_Float16)w.y;
    Wt[(n0 + 2) * KP + k] = (_Float16)w.z;
    Wt[(n0 + 3) * KP + k] = (_Float16)w.w;
  }
  __syncthreads();

  int wave = tid >> 6, lane = tid & 63;
  int m = lane & 15, quad = lane >> 4;
  int cw = wave * NC4;

  // B fragments: B[k=quad*8+j][n=cw+ct*16+m], register-resident for whole K
  half8 b[CT][KS];
#pragma unroll
  for (int ct = 0; ct < CT; ++ct)
#pragma unroll
    for (int s = 0; s < KS; ++s)
      b[ct][s] =
          *(half8*)&Wt[(size_t)(cw + ct * 16 + m) * KP + s * 32 + quad * 8];

  float bval[CT];  // bias per ct (col fixed per lane) — only used when !H16
#pragma unroll
  for (int ct = 0; ct < CT; ++ct)
    bval[ct] = H16 ? 0.f : bias[cw + ct * 16 + m];

  int nch = (M + 31) >> 5;
  for (int ch = blockIdx.x; ch < nch; ch += gridDim.x) {
    int r0 = ch << 5;
    f32x4 acc[2][CT];
#pragma unroll
    for (int rt = 0; rt < 2; ++rt)
#pragma unroll
      for (int ct = 0; ct < CT; ++ct) acc[rt][ct] = (f32x4){0.f, 0.f, 0.f, 0.f};

#pragma unroll
    for (int rt = 0; rt < 2; ++rt) {
      int row = r0 + rt * 16 + m;
      bool ok = row < M;
#pragma unroll
      for (int s = 0; s < KS; ++s) {
        half8 af = (half8)(_Float16)0;
        if (ok) {
          if (AH) {
            af = *(const half8*)((const _Float16*)A + (size_t)row * K +
                                 s * 32 + quad * 8);
          } else {
            const float* ap = (const float*)A + (size_t)row * K + quad * 8;
            float4 a0 = *(const float4*)(ap + s * 32);
            float4 a1 = *(const float4*)(ap + s * 32 + 4);
            af[0] = (_Float16)a0.x; af[1] = (_Float16)a0.y;
            af[2] = (_Float16)a0.z; af[3] = (_Float16)a0.w;
            af[4] = (_Float16)a1.x; af[5] = (_Float16)a1.y;
            af[6] = (_Float16)a1.z; af[7] = (_Float16)a1.w;
          }
        }
#pragma unroll
        for (int ct = 0; ct < CT; ++ct)
          acc[rt][ct] = __builtin_amdgcn_mfma_f32_16x16x32_f16(
              af, b[ct][s], acc[rt][ct], 0, 0, 0);
      }
    }

    // epilogue: C col = cw+ct*16+m, row = r0+rt*16+quad*4+i
#pragma unroll
    for (int rt = 0; rt < 2; ++rt) {
#pragma unroll
      for (int i = 0; i < 4; ++i) {
        int row = r0 + rt * 16 + quad * 4 + i;
        if (row >= M) continue;
        if (H16) {
          float d = dis[row];
#pragma unroll
          for (int ct = 0; ct < CT; ++ct)
            ((_Float16*)Cout)[(size_t)row * NCOL + cw + ct * 16 + m] =
                (_Float16)(acc[rt][ct][i] * d);
        } else {
#pragma unroll
          for (int ct = 0; ct < CT; ++ct)
            ((float*)Cout)[(size_t)row * NCOL + cw + ct * 16 + m] =
                acc[rt][ct][i] + bval[ct];
        }
      }
    }
  }
}

// Gather segment-sum over pre-scaled fp16 rows, one node per 64-lane wave,
// fp16 output + relu (layer 1). Lanes = EPW edge-slots x FC half8 chunks.
// h1[n][:] = relu(dis[n] * (sum_{s in N(n)} hws[s] + hws[n]) + bias), fp16.
template <int F>
__global__ __launch_bounds__(256) void gather_relu_kernel(
    const _Float16* __restrict__ hw, const float* __restrict__ dis,
    const int* __restrict__ off, const int* __restrict__ csr,
    const float* __restrict__ bias, _Float16* __restrict__ out, int N) {
  constexpr int FC = F / 8;
  constexpr int EPW = 64 / FC;
  int wave = threadIdx.x >> 6;
  int lane = threadIdx.x & 63;
  int eslot = lane / FC;
  int c = lane % FC;
  int n = blockIdx.x * 4 + wave;
  if (n >= N) return;

  const half8* hw8 = (const half8*)hw;
  float8 acc = {0.f, 0.f, 0.f, 0.f, 0.f, 0.f, 0.f, 0.f};
  if (eslot == 0)  // self loop
    acc = __builtin_convertvector(hw8[(size_t)n * FC + c], float8);

  int j0 = off[n], j1 = off[n + 1];
  int j = j0 + eslot;
  for (; j + 3 * EPW < j1; j += 4 * EPW) {
    int s0 = csr[j + 0 * EPW];
    int s1 = csr[j + 1 * EPW];
    int s2 = csr[j + 2 * EPW];
    int s3 = csr[j + 3 * EPW];
    half8 v0 = hw8[(size_t)s0 * FC + c];
    half8 v1 = hw8[(size_t)s1 * FC + c];
    half8 v2 = hw8[(size_t)s2 * FC + c];
    half8 v3 = hw8[(size_t)s3 * FC + c];
    acc += __builtin_convertvector(v0, float8);
    acc += __builtin_convertvector(v1, float8);
    acc += __builtin_convertvector(v2, float8);
    acc += __builtin_convertvector(v3, float8);
  }
  for (; j < j1; j += EPW)
    acc += __builtin_convertvector(hw8[(size_t)csr[j] * FC + c], float8);

#pragma unroll
  for (int st = FC; st < 64; st <<= 1) {
#pragma unroll
    for (int i = 0; i < 8; ++i) acc[i] += __shfl_xor(acc[i], st, 64);
  }

  if (eslot == 0) {
    float dn = dis[n];
    half8 h;
#pragma unroll
    for (int i = 0; i < 8; ++i)
      h[i] = (_Float16)fmaxf(fmaf(acc[i], dn, bias[c * 8 + i]), 0.f);
    *(half8*)(out + (size_t)n * F + c * 8) = h;
  }
}

// Layer-2 gather: fp32 output + bias, no relu. Same structure, F=64.
// out[n][:] = dis[n] * (sum_{s in N(n)} hws[s] + hws[n]) + bias  (fp32)
template <int F>
__global__ __launch_bounds__(256) void gather_f32_kernel(
    const _Float16* __restrict__ hw, const float* __restrict__ dis,
    const int* __restrict__ off, const int* __restrict__ csr,
    const float* __restrict__ bias, float* __restrict__ out, int N) {
  constexpr int FC = F / 8;
  constexpr int EPW = 64 / FC;
  int wave = threadIdx.x >> 6;
  int lane = threadIdx.x & 63;
  int eslot = lane / FC;
  int c = lane % FC;
  int n = blockIdx.x * 4 + wave;
  if (n >= N) return;

  const half8* hw8 = (const half8*)hw;
  float8 acc = {0.f, 0.f, 0.f, 0.f, 0.f, 0.f, 0.f, 0.f};
  if (eslot == 0)  // self loop
    acc = __builtin_convertvector(hw8[(size_t)n * FC + c], float8);

  int j0 = off[n], j1 = off[n + 1];
  int j = j0 + eslot;
  for (; j + 3 * EPW < j1; j += 4 * EPW) {
    int s0 = csr[j + 0 * EPW];
    int s1 = csr[j + 1 * EPW];
    int s2 = csr[j + 2 * EPW];
    int s3 = csr[j + 3 * EPW];
    half8 v0 = hw8[(size_t)s0 * FC + c];
    half8 v1 = hw8[(size_t)s1 * FC + c];
    half8 v2 = hw8[(size_t)s2 * FC + c];
    half8 v3 = hw8[(size_t)s3 * FC + c];
    acc += __builtin_convertvector(v0, float8);
    acc += __builtin_convertvector(v1, float8);
    acc += __builtin_convertvector(v2, float8);
    acc += __builtin_convertvector(v3, float8);
  }
  for (; j < j1; j += EPW)
    acc += __builtin_convertvector(hw8[(size_t)csr[j] * FC + c], float8);

#pragma unroll
  for (int st = FC; st < 64; st <<= 1) {
#pragma unroll
    for (int i = 0; i < 8; ++i) acc[i] += __shfl_xor(acc[i], st, 64);
  }

  if (eslot == 0) {
    float dn = dis[n];
    float4 b0 = *(const float4*)&bias[c * 8 + 0];
    float4 b1 = *(const float4*)&bias[c * 8 + 4];
    float4 r0 = make_float4(fmaf(acc[0], dn, b0.x), fmaf(acc[1], dn, b0.y),
                            fmaf(acc[2], dn, b0.z), fmaf(acc[3], dn, b0.w));
    float4 r1 = make_float4(fmaf(acc[4], dn, b1.x), fmaf(acc[5], dn, b1.y),
                            fmaf(acc[6], dn, b1.z), fmaf(acc[7], dn, b1.w));
    float* op = out + (size_t)n * F + c * 8;
    *(float4*)(op + 0) = r0;
    *(float4*)(op + 4) = r1;
  }
}

extern "C" void kernel_launch(void* const* d_in, const int* in_sizes, int n_in,
                              void* d_out, int out_size, void* d_ws,
                              size_t ws_size, hipStream_t stream) {
  const float* x = (const float*)d_in[0];
  const int* ei = (const int*)d_in[1];
  const float* W1 = (const float*)d_in[2];
  const float* b1 = (const float*)d_in[3];
  const float* W2 = (const float*)d_in[4];
  const float* b2 = (const float*)d_in[5];
  const float* Wc = (const float*)d_in[6];
  const float* bc = (const float*)d_in[7];

  int N = in_sizes[0] / DIN;
  int E = in_sizes[1] / 2;
  int nper = (N + 7) / 8;           // dst-range partition size
  float invn = 1.0f / (float)nper;  // deterministic partition map scale

  char* w = (char*)d_ws;
  size_t off = 0;
  auto alloc = [&](size_t bytes) {
    char* p = w + off;
    off += (bytes + 255) & ~(size_t)255;
    return p;
  };
  int* counts = (int*)alloc((size_t)N * 4);
  int* offsets = (int*)alloc((size_t)(N + 1) * 4);
  int* cursor = (int*)alloc((size_t)N * 4);
  int* csr = (int*)alloc((size_t)E * 4);
  float* dis = (float*)alloc((size_t)N * 4);
  int* blockSums = (int*)alloc((size_t)1024 * 4);
  _Float16* hw1 = (_Float16*)alloc((size_t)N * DIN * 2);  // fp16, dis-scaled
  _Float16* h1 = (_Float16*)alloc((size_t)N * HID * 2);   // fp16
  _Float16* hw2 = hw1;  // alias: hw1 dead after gather1

  float* out_h2 = (float*)d_out;             // output 0: h2 [N x 64]
  float* out_y = out_h2 + (size_t)N * FOUT;  // output 1: out [N x 64]

  hipMemsetAsync(counts, 0, (size_t)N * 4, stream);

  int egrid = (E + 255) / 256;
  int ngrid = (N + 255) / 256;  // scan chunk count G
  int wgrid = (N + 3) / 4;      // gathers: 4 nodes (waves) per block

  hist_kernel<<<egrid * 8, 256, 0, stream>>>(ei, E, counts, invn);
  block_sum_kernel<<<ngrid, 256, 0, stream>>>(counts, N, blockSums);
  scan_blocksums_kernel<<<1, 1024, 0, stream>>>(blockSums, ngrid);
  scan_apply_kernel<<<ngrid, 256, 0, stream>>>(counts, blockSums, N, E,
                                               offsets, cursor, dis);
  fill_kernel<<<egrid * 8, 256, 0, stream>>>(ei, E, cursor, csr, invn);

  // layer 1: hw1 = (x @ W1)*dis (fp16) ; h1 = relu(dn*Agg(hw1) + b1) (fp16)
  gemm_mfma_kernel<DIN, HID, false, true><<<512, 256, 0, stream>>>(
      x, W1, dis, nullptr, hw1, N);
  gather_relu_kernel<HID><<<wgrid, 256, 0, stream>>>(hw1, dis, offsets, csr,
                                                     b1, h1, N);

  // layer 2: hw2 = (h1 @ W2)*dis (fp16) ; h2 = dn*Agg(hw2) + b2 -> out_h2
  gemm_mfma_kernel<HID, FOUT, true, true><<<512, 256, 0, stream>>>(
      h1, W2, dis, nullptr, hw2, N);
  gather_f32_kernel<FOUT><<<wgrid, 256, 0, stream>>>(hw2, dis, offsets, csr,
                                                     b2, out_h2, N);

  // head: out_y = h2 @ Wc + bc (reads fp32 h2 from d_out, streaming MFMA)
  gemm_mfma_kernel<FOUT, FOUT, false, false><<<512, 256, 0, stream>>>(
      out_h2, Wc, nullptr, bc, out_y, N);
}

// Round 9
// 285.099 us; speedup vs baseline: 1.5485x; 1.0050x over previous
//
#include <hip/hip_runtime.h>

// GCN: h1 = relu(Agg(x@W1) + b1); h2 = Agg(h1@W2) + b2; out = h2@Wc + bc
// Agg = symmetric-normalized adjacency with self-loops (PyG GCNConv).
// R9: dispatch consolidation (11 -> 8 stream ops):
//  - gemm1 || hist fused in one fat kernel (disjoint block roles); hw1 is
//    stored UNSCALED fp16 and gather1 applies dis[s] per edge (L2-resident
//    200KB array, broadcast within slot) -> gemm1 no longer needs CSR.
//  - 3-kernel scan -> 1 kernel: each block sums counts[0..start) directly
//    for its base (coalesced, cheap), local-scans its chunk; node_init fused.
// CSR fill: XCD-partitioned (R5). GEMMs: v_mfma_f32_16x16x32_f16, W
// transposed to fp16 LDS, B-frags register-resident, grid-stride rows.
// Gathers: one node per wave, 16B/lane fp16 loads, fp32 accumulate.

#define DIN 128
#define HID 128
#define FOUT 64

using half8 = __attribute__((ext_vector_type(8))) _Float16;
using float8 = __attribute__((ext_vector_type(8))) float;
using f32x4 = __attribute__((ext_vector_type(4))) float;

// Deterministic dst->partition map (pure function; locality heuristic only).
__device__ inline int part_of(int d, float invn) {
  int p = (int)((float)d * invn);
  return p > 7 ? 7 : p;
}

// Fat kernel: blocks [0,gemmBlocks) do gemm1 (hw1 = x@W1, fp16 unscaled);
// blocks [gemmBlocks, ...) do the XCD-partitioned histogram.
__global__ __launch_bounds__(256) void gemm1_hist_kernel(
    const float* __restrict__ A, const float* __restrict__ W,
    _Float16* __restrict__ Cout, int M, const int* __restrict__ ei, int E,
    int* __restrict__ counts, float invn, int gemmBlocks) {
  constexpr int K = DIN, NCOL = HID;
  constexpr int KP = K + 8;      // half-stride: (K+8)*2 B is 16B-multiple
  constexpr int KS = K / 32;     // k-steps per MFMA chain
  constexpr int NC4 = NCOL / 4;  // cols per wave
  constexpr int CT = NC4 / 16;   // 16-col tiles per wave
  __shared__ _Float16 Wt[NCOL * KP];

  if (blockIdx.x >= gemmBlocks) {  // histogram role (no __syncthreads here)
    int b = blockIdx.x - gemmBlocks;
    int part = b & 7;
    int e = (b >> 3) * 256 + threadIdx.x;
    if (e < E) {
      int d = ei[E + e];
      if (part_of(d, invn) == part) atomicAdd(&counts[d], 1);
    }
    return;
  }

  int tid = threadIdx.x;
  // stage + transpose W -> Wt[n][k] fp16 (once per block)
  for (int i = tid; i < K * NCOL / 4; i += 256) {
    int k = i / (NCOL / 4);
    int n0 = (i % (NCOL / 4)) * 4;
    float4 w = *(const float4*)&W[(size_t)k * NCOL + n0];
    Wt[(n0 + 0) * KP + k] = (_Float16)w.x;
    Wt[(n0 + 1) * KP + k] = (_Float16)w.y;
    Wt[(n0 + 2) * KP + k] = (_Float16)w.z;
    Wt[(n0 + 3) * KP + k] = (_Float16)w.w;
  }
  __syncthreads();

  int wave = tid >> 6, lane = tid & 63;
  int m = lane & 15, quad = lane >> 4;
  int cw = wave * NC4;

  half8 b[CT][KS];  // B-frags register-resident for whole K
#pragma unroll
  for (int ct = 0; ct < CT; ++ct)
#pragma unroll
    for (int s = 0; s < KS; ++s)
      b[ct][s] =
          *(half8*)&Wt[(size_t)(cw + ct * 16 + m) * KP + s * 32 + quad * 8];

  int nch = (M + 31) >> 5;
  for (int ch = blockIdx.x; ch < nch; ch += gemmBlocks) {
    int r0 = ch << 5;
    f32x4 acc[2][CT];
#pragma unroll
    for (int rt = 0; rt < 2; ++rt)
#pragma unroll
      for (int ct = 0; ct < CT; ++ct) acc[rt][ct] = (f32x4){0.f, 0.f, 0.f, 0.f};

#pragma unroll
    for (int rt = 0; rt < 2; ++rt) {
      int row = r0 + rt * 16 + m;
      bool ok = row < M;
#pragma unroll
      for (int s = 0; s < KS; ++s) {
        half8 af = (half8)(_Float16)0;
        if (ok) {
          const float* ap = A + (size_t)row * K + quad * 8;
          float4 a0 = *(const float4*)(ap + s * 32);
          float4 a1 = *(const float4*)(ap + s * 32 + 4);
          af[0] = (_Float16)a0.x; af[1] = (_Float16)a0.y;
          af[2] = (_Float16)a0.z; af[3] = (_Float16)a0.w;
          af[4] = (_Float16)a1.x; af[5] = (_Float16)a1.y;
          af[6] = (_Float16)a1.z; af[7] = (_Float16)a1.w;
        }
#pragma unroll
        for (int ct = 0; ct < CT; ++ct)
          acc[rt][ct] = __builtin_amdgcn_mfma_f32_16x16x32_f16(
              af, b[ct][s], acc[rt][ct], 0, 0, 0);
      }
    }

#pragma unroll
    for (int rt = 0; rt < 2; ++rt) {
#pragma unroll
      for (int i = 0; i < 4; ++i) {
        int row = r0 + rt * 16 + quad * 4 + i;
        if (row >= M) continue;
#pragma unroll
        for (int ct = 0; ct < CT; ++ct)
          Cout[(size_t)row * NCOL + cw + ct * 16 + m] =
              (_Float16)acc[rt][ct][i];
      }
    }
  }
}

// One-kernel scan: block b computes base = sum counts[0..b*256) directly
// (coalesced strided read), local-scans its 256 chunk, fused node_init.
__global__ __launch_bounds__(256) void scan_fused_kernel(
    const int* __restrict__ counts, int N, int E, int* __restrict__ offsets,
    int* __restrict__ cursor, float* __restrict__ dis) {
  int t = threadIdx.x;
  int start = blockIdx.x * 256;

  int partial = 0;
  for (int i = t; i < start; i += 256) partial += counts[i];
#pragma unroll
  for (int off = 32; off > 0; off >>= 1)
    partial += __shfl_down(partial, off, 64);
  __shared__ int red[4];
  if ((t & 63) == 0) red[t >> 6] = partial;
  __syncthreads();
  int base = red[0] + red[1] + red[2] + red[3];

  int i = start + t;
  int c = (i < N) ? counts[i] : 0;
  __shared__ int s[256];
  s[t] = c;
  __syncthreads();
  for (int off = 1; off < 256; off <<= 1) {
    int u = 0;
    if (t >= off) u = s[t - off];
    __syncthreads();
    s[t] += u;
    __syncthreads();
  }
  int excl = s[t] - c + base;
  if (i < N) {
    offsets[i] = excl;
    cursor[i] = excl;
    dis[i] = rsqrtf((float)c + 1.0f);  // deg includes self-loop
  }
  if (i == N - 1) offsets[N] = E;
}

// Partitioned fill: only XCD (blockIdx&7) writes partition's csr/cursor range.
__global__ __launch_bounds__(256) void fill_kernel(
    const int* __restrict__ ei, int E, int* __restrict__ cursor,
    int* __restrict__ csr, float invn) {
  int part = blockIdx.x & 7;
  int e = (blockIdx.x >> 3) * 256 + threadIdx.x;
  if (e >= E) return;
  int d = ei[E + e];
  if (part_of(d, invn) != part) return;
  int s = ei[e];
  int p = atomicAdd(&cursor[d], 1);
  csr[p] = s;
}

// MFMA GEMM: C[M x NCOL] = A[M x K] @ W[K x NCOL](fp32), fp16 compute, fp32
// accumulate. AH: A fp16. H16: store fp16*dis[row]; else fp32 + bias.
template <int K, int NCOL, bool AH, bool H16>
__global__ __launch_bounds__(256) void gemm_mfma_kernel(
    const void* __restrict__ A, const float* __restrict__ W,
    const float* __restrict__ dis, const float* __restrict__ bias,
    void* __restrict__ Cout, int M) {
  constexpr int KP = K + 8;
  constexpr int KS = K / 32;
  constexpr int NC4 = NCOL / 4;
  constexpr int CT = NC4 / 16;
  __shared__ _Float16 Wt[NCOL * KP];

  int tid = threadIdx.x;
  for (int i = tid; i < K * NCOL / 4; i += 256) {
    int k = i / (NCOL / 4);
    int n0 = (i % (NCOL / 4)) * 4;
    float4 w = *(const float4*)&W[(size_t)k * NCOL + n0];
    Wt[(n0 + 0) * KP + k] = (_Float16)w.x;
    Wt[(n0 + 1) * KP + k] = (_Float16)w.y;
    Wt[(n0 + 2) * KP + k] = (_Float16)w.z;
    Wt[(n0 + 3) * KP + k] = (_Float16)w.w;
  }
  __syncthreads();

  int wave = tid >> 6, lane = tid & 63;
  int m = lane & 15, quad = lane >> 4;
  int cw = wave * NC4;

  half8 b[CT][KS];
#pragma unroll
  for (int ct = 0; ct < CT; ++ct)
#pragma unroll
    for (int s = 0; s < KS; ++s)
      b[ct][s] =
          *(half8*)&Wt[(size_t)(cw + ct * 16 + m) * KP + s * 32 + quad * 8];

  float bval[CT];
#pragma unroll
  for (int ct = 0; ct < CT; ++ct)
    bval[ct] = H16 ? 0.f : bias[cw + ct * 16 + m];

  int nch = (M + 31) >> 5;
  for (int ch = blockIdx.x; ch < nch; ch += gridDim.x) {
    int r0 = ch << 5;
    f32x4 acc[2][CT];
#pragma unroll
    for (int rt = 0; rt < 2; ++rt)
#pragma unroll
      for (int ct = 0; ct < CT; ++ct) acc[rt][ct] = (f32x4){0.f, 0.f, 0.f, 0.f};

#pragma unroll
    for (int rt = 0; rt < 2; ++rt) {
      int row = r0 + rt * 16 + m;
      bool ok = row < M;
#pragma unroll
      for (int s = 0; s < KS; ++s) {
        half8 af = (half8)(_Float16)0;
        if (ok) {
          if (AH) {
            af = *(const half8*)((const _Float16*)A + (size_t)row * K +
                                 s * 32 + quad * 8);
          } else {
            const float* ap = (const float*)A + (size_t)row * K + quad * 8;
            float4 a0 = *(const float4*)(ap + s * 32);
            float4 a1 = *(const float4*)(ap + s * 32 + 4);
            af[0] = (_Float16)a0.x; af[1] = (_Float16)a0.y;
            af[2] = (_Float16)a0.z; af[3] = (_Float16)a0.w;
            af[4] = (_Float16)a1.x; af[5] = (_Float16)a1.y;
            af[6] = (_Float16)a1.z; af[7] = (_Float16)a1.w;
          }
        }
#pragma unroll
        for (int ct = 0; ct < CT; ++ct)
          acc[rt][ct] = __builtin_amdgcn_mfma_f32_16x16x32_f16(
              af, b[ct][s], acc[rt][ct], 0, 0, 0);
      }
    }

#pragma unroll
    for (int rt = 0; rt < 2; ++rt) {
#pragma unroll
      for (int i = 0; i < 4; ++i) {
        int row = r0 + rt * 16 + quad * 4 + i;
        if (row >= M) continue;
        if (H16) {
          float d = dis[row];
#pragma unroll
          for (int ct = 0; ct < CT; ++ct)
            ((_Float16*)Cout)[(size_t)row * NCOL + cw + ct * 16 + m] =
                (_Float16)(acc[rt][ct][i] * d);
        } else {
#pragma unroll
          for (int ct = 0; ct < CT; ++ct)
            ((float*)Cout)[(size_t)row * NCOL + cw + ct * 16 + m] =
                acc[rt][ct][i] + bval[ct];
        }
      }
    }
  }
}

// Layer-1 gather over UNSCALED fp16 rows, per-edge dis[s] weight (broadcast
// load within slot), one node per wave. h1 = relu(dn*(sum hw[s]*ds + hw[n]*dn)
// + b1), fp16 out.
template <int F>
__global__ __launch_bounds__(256) void gather_relu_kernel(
    const _Float16* __restrict__ hw, const float* __restrict__ dis,
    const int* __restrict__ off, const int* __restrict__ csr,
    const float* __restrict__ bias, _Float16* __restrict__ out, int N) {
  constexpr int FC = F / 8;
  constexpr int EPW = 64 / FC;
  int wave = threadIdx.x >> 6;
  int lane = threadIdx.x & 63;
  int eslot = lane / FC;
  int c = lane % FC;
  int n = blockIdx.x * 4 + wave;
  if (n >= N) return;

  const half8* hw8 = (const half8*)hw;
  float dn = dis[n];
  float8 acc = {0.f, 0.f, 0.f, 0.f, 0.f, 0.f, 0.f, 0.f};
  if (eslot == 0)  // self loop: hw[n]*dn (outer *dn below gives dn^2)
    acc = __builtin_convertvector(hw8[(size_t)n * FC + c], float8) * dn;

  int j0 = off[n], j1 = off[n + 1];
  int j = j0 + eslot;
  for (; j + 3 * EPW < j1; j += 4 * EPW) {
    int s0 = csr[j + 0 * EPW];
    int s1 = csr[j + 1 * EPW];
    int s2 = csr[j + 2 * EPW];
    int s3 = csr[j + 3 * EPW];
    float d0 = dis[s0];
    float d1 = dis[s1];
    float d2 = dis[s2];
    float d3 = dis[s3];
    half8 v0 = hw8[(size_t)s0 * FC + c];
    half8 v1 = hw8[(size_t)s1 * FC + c];
    half8 v2 = hw8[(size_t)s2 * FC + c];
    half8 v3 = hw8[(size_t)s3 * FC + c];
    acc += __builtin_convertvector(v0, float8) * d0;
    acc += __builtin_convertvector(v1, float8) * d1;
    acc += __builtin_convertvector(v2, float8) * d2;
    acc += __builtin_convertvector(v3, float8) * d3;
  }
  for (; j < j1; j += EPW) {
    int s = csr[j];
    acc += __builtin_convertvector(hw8[(size_t)s * FC + c], float8) * dis[s];
  }

#pragma unroll
  for (int st = FC; st < 64; st <<= 1) {
#pragma unroll
    for (int i = 0; i < 8; ++i) acc[i] += __shfl_xor(acc[i], st, 64);
  }

  if (eslot == 0) {
    half8 h;
#pragma unroll
    for (int i = 0; i < 8; ++i)
      h[i] = (_Float16)fmaxf(fmaf(acc[i], dn, bias[c * 8 + i]), 0.f);
    *(half8*)(out + (size_t)n * F + c * 8) = h;
  }
}

// Layer-2 gather over PRE-SCALED fp16 rows (gemm2 epilogue applies dis[row]):
// out[n] = dn * (sum hws[s] + hws[n]) + b2, fp32 out (output 0).
template <int F>
__global__ __launch_bounds__(256) void gather_f32_kernel(
    const _Float16* __restrict__ hw, const float* __restrict__ dis,
    const int* __restrict__ off, const int* __restrict__ csr,
    const float* __restrict__ bias, float* __restrict__ out, int N) {
  constexpr int FC = F / 8;
  constexpr int EPW = 64 / FC;
  int wave = threadIdx.x >> 6;
  int lane = threadIdx.x & 63;
  int eslot = lane / FC;
  int c = lane % FC;
  int n = blockIdx.x * 4 + wave;
  if (n >= N) return;

  const half8* hw8 = (const half8*)hw;
  float8 acc = {0.f, 0.f, 0.f, 0.f, 0.f, 0.f, 0.f, 0.f};
  if (eslot == 0)  // self loop
    acc = __builtin_convertvector(hw8[(size_t)n * FC + c], float8);

  int j0 = off[n], j1 = off[n + 1];
  int j = j0 + eslot;
  for (; j + 3 * EPW < j1; j += 4 * EPW) {
    int s0 = csr[j + 0 * EPW];
    int s1 = csr[j + 1 * EPW];
    int s2 = csr[j + 2 * EPW];
    int s3 = csr[j + 3 * EPW];
    half8 v0 = hw8[(size_t)s0 * FC + c];
    half8 v1 = hw8[(size_t)s1 * FC + c];
    half8 v2 = hw8[(size_t)s2 * FC + c];
    half8 v3 = hw8[(size_t)s3 * FC + c];
    acc += __builtin_convertvector(v0, float8);
    acc += __builtin_convertvector(v1, float8);
    acc += __builtin_convertvector(v2, float8);
    acc += __builtin_convertvector(v3, float8);
  }
  for (; j < j1; j += EPW)
    acc += __builtin_convertvector(hw8[(size_t)csr[j] * FC + c], float8);

#pragma unroll
  for (int st = FC; st < 64; st <<= 1) {
#pragma unroll
    for (int i = 0; i < 8; ++i) acc[i] += __shfl_xor(acc[i], st, 64);
  }

  if (eslot == 0) {
    float dn = dis[n];
    float4 b0 = *(const float4*)&bias[c * 8 + 0];
    float4 b1 = *(const float4*)&bias[c * 8 + 4];
    float4 r0 = make_float4(fmaf(acc[0], dn, b0.x), fmaf(acc[1], dn, b0.y),
                            fmaf(acc[2], dn, b0.z), fmaf(acc[3], dn, b0.w));
    float4 r1 = make_float4(fmaf(acc[4], dn, b1.x), fmaf(acc[5], dn, b1.y),
                            fmaf(acc[6], dn, b1.z), fmaf(acc[7], dn, b1.w));
    float* op = out + (size_t)n * F + c * 8;
    *(float4*)(op + 0) = r0;
    *(float4*)(op + 4) = r1;
  }
}

extern "C" void kernel_launch(void* const* d_in, const int* in_sizes, int n_in,
                              void* d_out, int out_size, void* d_ws,
                              size_t ws_size, hipStream_t stream) {
  const float* x = (const float*)d_in[0];
  const int* ei = (const int*)d_in[1];
  const float* W1 = (const float*)d_in[2];
  const float* b1 = (const float*)d_in[3];
  const float* W2 = (const float*)d_in[4];
  const float* b2 = (const float*)d_in[5];
  const float* Wc = (const float*)d_in[6];
  const float* bc = (const float*)d_in[7];

  int N = in_sizes[0] / DIN;
  int E = in_sizes[1] / 2;
  int nper = (N + 7) / 8;           // dst-range partition size
  float invn = 1.0f / (float)nper;  // deterministic partition map scale

  char* w = (char*)d_ws;
  size_t off = 0;
  auto alloc = [&](size_t bytes) {
    char* p = w + off;
    off += (bytes + 255) & ~(size_t)255;
    return p;
  };
  int* counts = (int*)alloc((size_t)N * 4);
  int* offsets = (int*)alloc((size_t)(N + 1) * 4);
  int* cursor = (int*)alloc((size_t)N * 4);
  int* csr = (int*)alloc((size_t)E * 4);
  float* dis = (float*)alloc((size_t)N * 4);
  _Float16* hw1 = (_Float16*)alloc((size_t)N * DIN * 2);  // fp16, UNscaled
  _Float16* h1 = (_Float16*)alloc((size_t)N * HID * 2);   // fp16
  _Float16* hw2 = hw1;  // alias: hw1 dead after gather1

  float* out_h2 = (float*)d_out;             // output 0: h2 [N x 64]
  float* out_y = out_h2 + (size_t)N * FOUT;  // output 1: out [N x 64]

  hipMemsetAsync(counts, 0, (size_t)N * 4, stream);

  int egrid = (E + 255) / 256;
  int ngrid = (N + 255) / 256;
  int wgrid = (N + 3) / 4;  // gathers: 4 nodes (waves) per block

  // gemm1 (blocks 0..511) || histogram (blocks 512..)
  gemm1_hist_kernel<<<512 + egrid * 8, 256, 0, stream>>>(
      x, W1, hw1, N, ei, E, counts, invn, 512);
  scan_fused_kernel<<<ngrid, 256, 0, stream>>>(counts, N, E, offsets, cursor,
                                               dis);
  fill_kernel<<<egrid * 8, 256, 0, stream>>>(ei, E, cursor, csr, invn);

  // h1 = relu(dn*Agg(hw1*ds) + b1) (fp16)
  gather_relu_kernel<HID><<<wgrid, 256, 0, stream>>>(hw1, dis, offsets, csr,
                                                     b1, h1, N);

  // hw2 = (h1 @ W2)*dis (fp16) ; h2 = dn*Agg(hw2) + b2 -> out_h2
  gemm_mfma_kernel<HID, FOUT, true, true><<<512, 256, 0, stream>>>(
      h1, W2, dis, nullptr, hw2, N);
  gather_f32_kernel<FOUT><<<wgrid, 256, 0, stream>>>(hw2, dis, offsets, csr,
                                                     b2, out_h2, N);

  // head: out_y = h2 @ Wc + bc (reads fp32 h2 from d_out, streaming MFMA)
  gemm_mfma_kernel<FOUT, FOUT, false, false><<<512, 256, 0, stream>>>(
      out_h2, Wc, nullptr, bc, out_y, N);
}

// Round 10
// 273.764 us; speedup vs baseline: 1.6126x; 1.0414x over previous
//
#include <hip/hip_runtime.h>

// GCN: h1 = relu(Agg(x@W1) + b1); h2 = Agg(h1@W2) + b2; out = h2@Wc + bc
// Agg = symmetric-normalized adjacency with self-loops (PyG GCNConv).
// R10: GEMMs rewritten as LDS-staged tile kernels. R9's fragment-direct
// A loads were row-scattered (16 rows/wave-instr, MfmaUtil 1%, 50us);
// now: 64-row A tile staged coalesced -> fp16 LDS (KP=K+8), A-frags via
// ds_read_b128; B-frags via coalesced scalar global reads of L2-hot W
// (no LDS W transpose -> kills R9's 4M bank-conflict cycles from 2-byte
// scattered ds_writes). One 64-row tile per block.
// CSR build: XCD-partitioned hist/fill (R5), 1-kernel scan (R9).
// Gathers: one node per wave, 16B/lane fp16 loads, fp32 accumulate.

#define DIN 128
#define HID 128
#define FOUT 64

using half8 = __attribute__((ext_vector_type(8))) _Float16;
using float8 = __attribute__((ext_vector_type(8))) float;
using f32x4 = __attribute__((ext_vector_type(4))) float;

// Deterministic dst->partition map (pure function; locality heuristic only).
__device__ inline int part_of(int d, float invn) {
  int p = (int)((float)d * invn);
  return p > 7 ? 7 : p;
}

// Partitioned histogram: block b = chunk (b>>3) x partition (b&7).
__global__ __launch_bounds__(256) void hist_kernel(
    const int* __restrict__ ei, int E, int* __restrict__ counts, float invn) {
  int part = blockIdx.x & 7;
  int e = (blockIdx.x >> 3) * 256 + threadIdx.x;
  if (e >= E) return;
  int d = ei[E + e];
  if (part_of(d, invn) == part) atomicAdd(&counts[d], 1);
}

// One-kernel scan: block b computes base = sum counts[0..b*256) directly
// (coalesced strided read), local-scans its 256 chunk, fused node_init.
__global__ __launch_bounds__(256) void scan_fused_kernel(
    const int* __restrict__ counts, int N, int E, int* __restrict__ offsets,
    int* __restrict__ cursor, float* __restrict__ dis) {
  int t = threadIdx.x;
  int start = blockIdx.x * 256;

  int partial = 0;
  for (int i = t; i < start; i += 256) partial += counts[i];
#pragma unroll
  for (int off = 32; off > 0; off >>= 1)
    partial += __shfl_down(partial, off, 64);
  __shared__ int red[4];
  if ((t & 63) == 0) red[t >> 6] = partial;
  __syncthreads();
  int base = red[0] + red[1] + red[2] + red[3];

  int i = start + t;
  int c = (i < N) ? counts[i] : 0;
  __shared__ int s[256];
  s[t] = c;
  __syncthreads();
  for (int off = 1; off < 256; off <<= 1) {
    int u = 0;
    if (t >= off) u = s[t - off];
    __syncthreads();
    s[t] += u;
    __syncthreads();
  }
  int excl = s[t] - c + base;
  if (i < N) {
    offsets[i] = excl;
    cursor[i] = excl;
    dis[i] = rsqrtf((float)c + 1.0f);  // deg includes self-loop
  }
  if (i == N - 1) offsets[N] = E;
}

// Partitioned fill: only XCD (blockIdx&7) writes partition's csr/cursor range.
__global__ __launch_bounds__(256) void fill_kernel(
    const int* __restrict__ ei, int E, int* __restrict__ cursor,
    int* __restrict__ csr, float invn) {
  int part = blockIdx.x & 7;
  int e = (blockIdx.x >> 3) * 256 + threadIdx.x;
  if (e >= E) return;
  int d = ei[E + e];
  if (part_of(d, invn) != part) return;
  int s = ei[e];
  int p = atomicAdd(&cursor[d], 1);
  csr[p] = s;
}

// Tile MFMA GEMM: C[M x NCOL] = A[M x K] @ W[K x NCOL](fp32), fp16 compute,
// fp32 accumulate. One 64-row tile per block.
// AH: A fp16 (else fp32, converted during staging).
// H16: store fp16 (gather operand; *dis[row] if SCALE); else fp32 + bias.
template <int K, int NCOL, bool AH, bool H16, bool SCALE>
__global__ __launch_bounds__(256) void gemm_tile_kernel(
    const void* __restrict__ A, const float* __restrict__ W,
    const float* __restrict__ dis, const float* __restrict__ bias,
    void* __restrict__ Cout, int M) {
  constexpr int KP = K + 8;     // halfs; (K+8)*2 B is a 16B multiple
  constexpr int KS = K / 32;    // k-steps
  constexpr int G8 = K / 8;     // half8 groups per row
  constexpr int NW = NCOL / 4;  // cols per wave
  constexpr int CT = NW / 16;   // 16-col tiles per wave
  __shared__ _Float16 As[64 * KP];

  int tid = threadIdx.x;
  int r0 = blockIdx.x * 64;

  // stage A tile (64 x K) -> fp16 LDS, coalesced global reads
  for (int g = tid; g < 64 * G8; g += 256) {
    int row = g / G8, c8 = g % G8;
    half8 h = (half8)(_Float16)0;
    if (r0 + row < M) {
      if (AH) {
        h = *(const half8*)((const _Float16*)A + (size_t)(r0 + row) * K +
                            c8 * 8);
      } else {
        const float* ap = (const float*)A + (size_t)(r0 + row) * K + c8 * 8;
        float4 a0 = *(const float4*)ap;
        float4 a1 = *(const float4*)(ap + 4);
        h[0] = (_Float16)a0.x; h[1] = (_Float16)a0.y;
        h[2] = (_Float16)a0.z; h[3] = (_Float16)a0.w;
        h[4] = (_Float16)a1.x; h[5] = (_Float16)a1.y;
        h[6] = (_Float16)a1.z; h[7] = (_Float16)a1.w;
      }
    }
    *(half8*)&As[row * KP + c8 * 8] = h;
  }

  int wave = tid >> 6, lane = tid & 63;
  int m = lane & 15, quad = lane >> 4;
  int cw = wave * NW;

  // B fragments: B[k=quad*8+j][n=cw+ct*16+m] via scalar global loads of W
  // (coalesced across m within each quad; W is 64KB, L2-resident).
  half8 b[CT][KS];
#pragma unroll
  for (int ct = 0; ct < CT; ++ct) {
    int n = cw + ct * 16 + m;
#pragma unroll
    for (int s = 0; s < KS; ++s) {
#pragma unroll
      for (int j = 0; j < 8; ++j)
        b[ct][s][j] = (_Float16)W[(size_t)(s * 32 + quad * 8 + j) * NCOL + n];
    }
  }

  float bval[CT];
#pragma unroll
  for (int ct = 0; ct < CT; ++ct)
    bval[ct] = H16 ? 0.f : bias[cw + ct * 16 + m];

  __syncthreads();

  f32x4 acc[4][CT];
#pragma unroll
  for (int rt = 0; rt < 4; ++rt)
#pragma unroll
    for (int ct = 0; ct < CT; ++ct) acc[rt][ct] = (f32x4){0.f, 0.f, 0.f, 0.f};

#pragma unroll
  for (int rt = 0; rt < 4; ++rt) {
#pragma unroll
    for (int s = 0; s < KS; ++s) {
      half8 af = *(half8*)&As[(rt * 16 + m) * KP + s * 32 + quad * 8];
#pragma unroll
      for (int ct = 0; ct < CT; ++ct)
        acc[rt][ct] = __builtin_amdgcn_mfma_f32_16x16x32_f16(
            af, b[ct][s], acc[rt][ct], 0, 0, 0);
    }
  }

  // epilogue: C col = cw+ct*16+m, row = r0+rt*16+quad*4+i
#pragma unroll
  for (int rt = 0; rt < 4; ++rt) {
#pragma unroll
    for (int i = 0; i < 4; ++i) {
      int row = r0 + rt * 16 + quad * 4 + i;
      if (row >= M) continue;
      if (H16) {
        float d = SCALE ? dis[row] : 1.0f;
#pragma unroll
        for (int ct = 0; ct < CT; ++ct)
          ((_Float16*)Cout)[(size_t)row * NCOL + cw + ct * 16 + m] =
              (_Float16)(acc[rt][ct][i] * d);
      } else {
#pragma unroll
        for (int ct = 0; ct < CT; ++ct)
          ((float*)Cout)[(size_t)row * NCOL + cw + ct * 16 + m] =
              acc[rt][ct][i] + bval[ct];
      }
    }
  }
}

// Layer-1 gather over UNSCALED fp16 rows, per-edge dis[s] weight, one node
// per wave. h1 = relu(dn*(sum hw[s]*ds + hw[n]*dn) + b1), fp16 out.
template <int F>
__global__ __launch_bounds__(256) void gather_relu_kernel(
    const _Float16* __restrict__ hw, const float* __restrict__ dis,
    const int* __restrict__ off, const int* __restrict__ csr,
    const float* __restrict__ bias, _Float16* __restrict__ out, int N) {
  constexpr int FC = F / 8;
  constexpr int EPW = 64 / FC;
  int wave = threadIdx.x >> 6;
  int lane = threadIdx.x & 63;
  int eslot = lane / FC;
  int c = lane % FC;
  int n = blockIdx.x * 4 + wave;
  if (n >= N) return;

  const half8* hw8 = (const half8*)hw;
  float dn = dis[n];
  float8 acc = {0.f, 0.f, 0.f, 0.f, 0.f, 0.f, 0.f, 0.f};
  if (eslot == 0)  // self loop: hw[n]*dn (outer *dn below gives dn^2)
    acc = __builtin_convertvector(hw8[(size_t)n * FC + c], float8) * dn;

  int j0 = off[n], j1 = off[n + 1];
  int j = j0 + eslot;
  for (; j + 3 * EPW < j1; j += 4 * EPW) {
    int s0 = csr[j + 0 * EPW];
    int s1 = csr[j + 1 * EPW];
    int s2 = csr[j + 2 * EPW];
    int s3 = csr[j + 3 * EPW];
    float d0 = dis[s0];
    float d1 = dis[s1];
    float d2 = dis[s2];
    float d3 = dis[s3];
    half8 v0 = hw8[(size_t)s0 * FC + c];
    half8 v1 = hw8[(size_t)s1 * FC + c];
    half8 v2 = hw8[(size_t)s2 * FC + c];
    half8 v3 = hw8[(size_t)s3 * FC + c];
    acc += __builtin_convertvector(v0, float8) * d0;
    acc += __builtin_convertvector(v1, float8) * d1;
    acc += __builtin_convertvector(v2, float8) * d2;
    acc += __builtin_convertvector(v3, float8) * d3;
  }
  for (; j < j1; j += EPW) {
    int s = csr[j];
    acc += __builtin_convertvector(hw8[(size_t)s * FC + c], float8) * dis[s];
  }

#pragma unroll
  for (int st = FC; st < 64; st <<= 1) {
#pragma unroll
    for (int i = 0; i < 8; ++i) acc[i] += __shfl_xor(acc[i], st, 64);
  }

  if (eslot == 0) {
    half8 h;
#pragma unroll
    for (int i = 0; i < 8; ++i)
      h[i] = (_Float16)fmaxf(fmaf(acc[i], dn, bias[c * 8 + i]), 0.f);
    *(half8*)(out + (size_t)n * F + c * 8) = h;
  }
}

// Layer-2 gather over PRE-SCALED fp16 rows (gemm2 epilogue applies dis[row]):
// out[n] = dn * (sum hws[s] + hws[n]) + b2, fp32 out (output 0).
template <int F>
__global__ __launch_bounds__(256) void gather_f32_kernel(
    const _Float16* __restrict__ hw, const float* __restrict__ dis,
    const int* __restrict__ off, const int* __restrict__ csr,
    const float* __restrict__ bias, float* __restrict__ out, int N) {
  constexpr int FC = F / 8;
  constexpr int EPW = 64 / FC;
  int wave = threadIdx.x >> 6;
  int lane = threadIdx.x & 63;
  int eslot = lane / FC;
  int c = lane % FC;
  int n = blockIdx.x * 4 + wave;
  if (n >= N) return;

  const half8* hw8 = (const half8*)hw;
  float8 acc = {0.f, 0.f, 0.f, 0.f, 0.f, 0.f, 0.f, 0.f};
  if (eslot == 0)  // self loop
    acc = __builtin_convertvector(hw8[(size_t)n * FC + c], float8);

  int j0 = off[n], j1 = off[n + 1];
  int j = j0 + eslot;
  for (; j + 3 * EPW < j1; j += 4 * EPW) {
    int s0 = csr[j + 0 * EPW];
    int s1 = csr[j + 1 * EPW];
    int s2 = csr[j + 2 * EPW];
    int s3 = csr[j + 3 * EPW];
    half8 v0 = hw8[(size_t)s0 * FC + c];
    half8 v1 = hw8[(size_t)s1 * FC + c];
    half8 v2 = hw8[(size_t)s2 * FC + c];
    half8 v3 = hw8[(size_t)s3 * FC + c];
    acc += __builtin_convertvector(v0, float8);
    acc += __builtin_convertvector(v1, float8);
    acc += __builtin_convertvector(v2, float8);
    acc += __builtin_convertvector(v3, float8);
  }
  for (; j < j1; j += EPW)
    acc += __builtin_convertvector(hw8[(size_t)csr[j] * FC + c], float8);

#pragma unroll
  for (int st = FC; st < 64; st <<= 1) {
#pragma unroll
    for (int i = 0; i < 8; ++i) acc[i] += __shfl_xor(acc[i], st, 64);
  }

  if (eslot == 0) {
    float dn = dis[n];
    float4 b0 = *(const float4*)&bias[c * 8 + 0];
    float4 b1 = *(const float4*)&bias[c * 8 + 4];
    float4 r0 = make_float4(fmaf(acc[0], dn, b0.x), fmaf(acc[1], dn, b0.y),
                            fmaf(acc[2], dn, b0.z), fmaf(acc[3], dn, b0.w));
    float4 r1 = make_float4(fmaf(acc[4], dn, b1.x), fmaf(acc[5], dn, b1.y),
                            fmaf(acc[6], dn, b1.z), fmaf(acc[7], dn, b1.w));
    float* op = out + (size_t)n * F + c * 8;
    *(float4*)(op + 0) = r0;
    *(float4*)(op + 4) = r1;
  }
}

extern "C" void kernel_launch(void* const* d_in, const int* in_sizes, int n_in,
                              void* d_out, int out_size, void* d_ws,
                              size_t ws_size, hipStream_t stream) {
  const float* x = (const float*)d_in[0];
  const int* ei = (const int*)d_in[1];
  const float* W1 = (const float*)d_in[2];
  const float* b1 = (const float*)d_in[3];
  const float* W2 = (const float*)d_in[4];
  const float* b2 = (const float*)d_in[5];
  const float* Wc = (const float*)d_in[6];
  const float* bc = (const float*)d_in[7];

  int N = in_sizes[0] / DIN;
  int E = in_sizes[1] / 2;
  int nper = (N + 7) / 8;           // dst-range partition size
  float invn = 1.0f / (float)nper;  // deterministic partition map scale

  char* w = (char*)d_ws;
  size_t off = 0;
  auto alloc = [&](size_t bytes) {
    char* p = w + off;
    off += (bytes + 255) & ~(size_t)255;
    return p;
  };
  int* counts = (int*)alloc((size_t)N * 4);
  int* offsets = (int*)alloc((size_t)(N + 1) * 4);
  int* cursor = (int*)alloc((size_t)N * 4);
  int* csr = (int*)alloc((size_t)E * 4);
  float* dis = (float*)alloc((size_t)N * 4);
  _Float16* hw1 = (_Float16*)alloc((size_t)N * DIN * 2);  // fp16, UNscaled
  _Float16* h1 = (_Float16*)alloc((size_t)N * HID * 2);   // fp16
  _Float16* hw2 = hw1;  // alias: hw1 dead after gather1

  float* out_h2 = (float*)d_out;             // output 0: h2 [N x 64]
  float* out_y = out_h2 + (size_t)N * FOUT;  // output 1: out [N x 64]

  hipMemsetAsync(counts, 0, (size_t)N * 4, stream);

  int egrid = (E + 255) / 256;
  int ngrid = (N + 255) / 256;
  int wgrid = (N + 3) / 4;    // gathers: 4 nodes (waves) per block
  int tgrid = (N + 63) / 64;  // gemm: one 64-row tile per block

  hist_kernel<<<egrid * 8, 256, 0, stream>>>(ei, E, counts, invn);
  scan_fused_kernel<<<ngrid, 256, 0, stream>>>(counts, N, E, offsets, cursor,
                                               dis);
  fill_kernel<<<egrid * 8, 256, 0, stream>>>(ei, E, cursor, csr, invn);

  // layer 1: hw1 = x @ W1 (fp16, unscaled)
  gemm_tile_kernel<DIN, HID, false, true, false><<<tgrid, 256, 0, stream>>>(
      x, W1, nullptr, nullptr, hw1, N);
  // h1 = relu(dn*Agg(hw1*ds) + b1) (fp16)
  gather_relu_kernel<HID><<<wgrid, 256, 0, stream>>>(hw1, dis, offsets, csr,
                                                     b1, h1, N);

  // hw2 = (h1 @ W2)*dis (fp16) ; h2 = dn*Agg(hw2) + b2 -> out_h2
  gemm_tile_kernel<HID, FOUT, true, true, true><<<tgrid, 256, 0, stream>>>(
      h1, W2, dis, nullptr, hw2, N);
  gather_f32_kernel<FOUT><<<wgrid, 256, 0, stream>>>(hw2, dis, offsets, csr,
                                                     b2, out_h2, N);

  // head: out_y = h2 @ Wc + bc (fp32 h2 from d_out, streaming tile MFMA)
  gemm_tile_kernel<FOUT, FOUT, false, false, false><<<tgrid, 256, 0, stream>>>(
      out_h2, Wc, nullptr, bc, out_y, N);
}